// Round 8
// baseline (176.837 us; speedup 1.0000x reference)
//
#include <hip/hip_runtime.h>

#define BB 2
#define CCH 64
#define LLEN 16384
#define DM 128
#define NCHK 512
#define TCHK 32
#define NGRP 32
#define JG 16
#define NG 4

// workspace offsets (floats). hend aliases xc (dead after k2); hlocal in old hin slot;
// y overwrites dt in k5. wc + k4 small buffers alias ym (dead until k6).
#define OFF_XC   0ull
#define OFF_HEND 0ull
#define OFF_HLOC 2097152ull
#define OFF_Z    4194304ull
#define OFF_U    8388608ull
#define OFF_DT   12582912ull
#define OFF_BM   16777216ull
#define OFF_CM   17301504ull
#define OFF_DTS  17825792ull
#define OFF_YM   17956864ull
#define OFF_WC   17956864ull
// k4 scratch inside ym region (dead between k2b and k6):
#define OFF_CUMDT (17956864ull + 450000ull)
#define OFF_GEND  (OFF_CUMDT + 131072ull)
#define OFF_GDT   (OFF_GEND + 131072ull)
#define OFF_GINIT (OFF_GDT + 8192ull)
#define OFF_STAT 20054016ull

__device__ __forceinline__ float fsilu(float v) {
  return v * __builtin_amdgcn_rcpf(1.f + __expf(-v));
}
__device__ __forceinline__ float fsoftplus(float v) {
  return v > 20.f ? v : __logf(1.f + __expf(v));
}

// K1: xz = xr @ in_proj_w^T ; split into xc (e<128) and z (e>=128)
__global__ __launch_bounds__(256) void k1_inproj(
    const float* __restrict__ x, const float* __restrict__ w,
    float* __restrict__ xc, float* __restrict__ z)
{
  const int b = blockIdx.z;
  const int l0 = blockIdx.x * 64;
  const int e0 = blockIdx.y * 64;
  __shared__ float As[64][65];
  __shared__ float Bs[64][65];
  const int t = threadIdx.x;
#pragma unroll
  for (int i = 0; i < 16; i++) {
    int idx = t + i * 256;
    int c = idx >> 6, tok = idx & 63;
    As[c][tok] = x[(size_t)(b * CCH + c) * LLEN + l0 + tok];
  }
#pragma unroll
  for (int i = 0; i < 16; i++) {
    int idx = t + i * 256;
    int e = idx >> 6, c = idx & 63;
    Bs[c][e] = w[(e0 + e) * CCH + c];
  }
  __syncthreads();
  const int tm = (t & 15) * 4;
  const int tn = (t >> 4) * 4;
  float acc[4][4] = {};
  for (int c = 0; c < 64; c++) {
    float a0 = As[c][tm + 0], a1 = As[c][tm + 1], a2 = As[c][tm + 2], a3 = As[c][tm + 3];
    float b0 = Bs[c][tn + 0], b1 = Bs[c][tn + 1], b2 = Bs[c][tn + 2], b3 = Bs[c][tn + 3];
    acc[0][0] += a0 * b0; acc[0][1] += a0 * b1; acc[0][2] += a0 * b2; acc[0][3] += a0 * b3;
    acc[1][0] += a1 * b0; acc[1][1] += a1 * b1; acc[1][2] += a1 * b2; acc[1][3] += a1 * b3;
    acc[2][0] += a2 * b0; acc[2][1] += a2 * b1; acc[2][2] += a2 * b2; acc[2][3] += a2 * b3;
    acc[3][0] += a3 * b0; acc[3][1] += a3 * b1; acc[3][2] += a3 * b2; acc[3][3] += a3 * b3;
  }
  float* dst = (e0 < DM) ? (xc + e0) : (z + (e0 - DM));
#pragma unroll
  for (int i = 0; i < 4; i++) {
    int l = l0 + tm + i;
    float4 v = make_float4(acc[i][0], acc[i][1], acc[i][2], acc[i][3]);
    *reinterpret_cast<float4*>(dst + (size_t)(b * LLEN + l) * DM + tn) = v;
  }
}

// K0: W_comb[160][128]: rows 0..127 = dtw @ xpw[0:4]; rows 128..159 = xpw[4:36]
__global__ __launch_bounds__(256) void k0_wcomb(
    const float* __restrict__ xpw, const float* __restrict__ dtw, float* __restrict__ wc)
{
  int i = blockIdx.x * 256 + threadIdx.x;
  if (i >= 160 * 128) return;
  int e = i >> 7, dd = i & 127;
  float v;
  if (e < 128) {
    v = dtw[e * 4 + 0] * xpw[0 * 128 + dd] + dtw[e * 4 + 1] * xpw[1 * 128 + dd]
      + dtw[e * 4 + 2] * xpw[2 * 128 + dd] + dtw[e * 4 + 3] * xpw[3 * 128 + dd];
  } else {
    v = xpw[(e - 128 + 4) * 128 + dd];
  }
  wc[i] = v;
}

// K2a: u = silu(causal_conv4(xc) + cb). Block = 64 tokens x 128 d; thread = 8 tok x 4 d.
__global__ __launch_bounds__(256) void k2a_conv(
    const float* __restrict__ xc, const float* __restrict__ cw, const float* __restrict__ cb,
    float* __restrict__ u)
{
  const int t = threadIdx.x;
  const int d4 = (t & 31) * 4;
  const int tg = t >> 5;
  const int tok0 = blockIdx.x * 64 + tg * 8;
  const int l0 = tok0 & (LLEN - 1);
  float4 w0 = *reinterpret_cast<const float4*>(cw + (d4 + 0) * 4);
  float4 w1 = *reinterpret_cast<const float4*>(cw + (d4 + 1) * 4);
  float4 w2 = *reinterpret_cast<const float4*>(cw + (d4 + 2) * 4);
  float4 w3 = *reinterpret_cast<const float4*>(cw + (d4 + 3) * 4);
  float4 bias = *reinterpret_cast<const float4*>(cb + d4);
  float4 row[11];
#pragma unroll
  for (int r = 0; r < 11; r++) {
    int l = l0 - 3 + r;
    if (l < 0) row[r] = make_float4(0.f, 0.f, 0.f, 0.f);
    else row[r] = *reinterpret_cast<const float4*>(xc + (size_t)(tok0 - 3 + r) * DM + d4);
  }
#pragma unroll
  for (int j = 0; j < 8; j++) {
    float4 acc;
    acc.x = bias.x + w0.x * row[j].x + w0.y * row[j+1].x + w0.z * row[j+2].x + w0.w * row[j+3].x;
    acc.y = bias.y + w1.x * row[j].y + w1.y * row[j+1].y + w1.z * row[j+2].y + w1.w * row[j+3].y;
    acc.z = bias.z + w2.x * row[j].z + w2.y * row[j+1].z + w2.z * row[j+2].z + w2.w * row[j+3].z;
    acc.w = bias.w + w3.x * row[j].w + w3.y * row[j+1].w + w3.z * row[j+2].w + w3.w * row[j+3].w;
    acc.x = fsilu(acc.x); acc.y = fsilu(acc.y); acc.z = fsilu(acc.z); acc.w = fsilu(acc.w);
    *reinterpret_cast<float4*>(u + (size_t)(tok0 + j) * DM + d4) = acc;
  }
}

// K2b: dbc160 = u @ W_comb^T. M=BL, N=160 (5 tiles of 32), K=128 (2 passes of BK=64).
// 128 threads, micro-tile 4 tok x 4 e -> VALU-bound (16 FMA per 2 ds_read_b128).
__global__ __launch_bounds__(128) void k2b_proj(
    const float* __restrict__ u, const float* __restrict__ wc, const float* __restrict__ dtpb,
    float* __restrict__ dt, float* __restrict__ bm, float* __restrict__ cm)
{
  const int tok0 = blockIdx.x * 64;
  const int e0 = blockIdx.y * 32;
  const int t = threadIdx.x;
  __shared__ float As[64][65];   // [k][tok]
  __shared__ float Bs[64][33];   // [k][e]
  const int tm = (t & 15) * 4;   // token offset
  const int tn = (t >> 4) * 4;   // e offset 0..28
  float acc[4][4] = {};
  for (int kb = 0; kb < 2; kb++) {
#pragma unroll
    for (int i = 0; i < 32; i++) {
      int idx = t + i * 128;
      int k = idx & 63, tok = idx >> 6;
      As[k][tok] = u[(size_t)(tok0 + tok) * DM + kb * 64 + k];
    }
#pragma unroll
    for (int i = 0; i < 16; i++) {
      int idx = t + i * 128;
      int k = idx & 63, e = idx >> 6;
      Bs[k][e] = wc[(e0 + e) * DM + kb * 64 + k];
    }
    __syncthreads();
#pragma unroll 4
    for (int k = 0; k < 64; k++) {
      float a0 = As[k][tm + 0], a1 = As[k][tm + 1], a2 = As[k][tm + 2], a3 = As[k][tm + 3];
      float b0 = Bs[k][tn + 0], b1 = Bs[k][tn + 1], b2 = Bs[k][tn + 2], b3 = Bs[k][tn + 3];
      acc[0][0] += a0 * b0; acc[0][1] += a0 * b1; acc[0][2] += a0 * b2; acc[0][3] += a0 * b3;
      acc[1][0] += a1 * b0; acc[1][1] += a1 * b1; acc[1][2] += a1 * b2; acc[1][3] += a1 * b3;
      acc[2][0] += a2 * b0; acc[2][1] += a2 * b1; acc[2][2] += a2 * b2; acc[2][3] += a2 * b3;
      acc[3][0] += a3 * b0; acc[3][1] += a3 * b1; acc[3][2] += a3 * b2; acc[3][3] += a3 * b3;
    }
    __syncthreads();
  }
  // stage results in LDS (over As memory) for coalesced writeback: Cs[tok][e], stride 33
  float* Cs = &As[0][0];
#pragma unroll
  for (int i = 0; i < 4; i++) {
#pragma unroll
    for (int j = 0; j < 4; j++) Cs[(tm + i) * 33 + tn + j] = acc[i][j];
  }
  __syncthreads();
  if (e0 < DM) {
#pragma unroll
    for (int i = 0; i < 16; i++) {
      int idx = t + i * 128;
      int tok = idx >> 5, e = idx & 31;
      float v = fsoftplus(Cs[tok * 33 + e] + dtpb[e0 + e]);
      dt[(size_t)(tok0 + tok) * DM + e0 + e] = v;
    }
  } else {
#pragma unroll
    for (int i = 0; i < 16; i++) {
      int idx = t + i * 128;
      int tok = idx >> 5, e = idx & 31;
      float v = Cs[tok * 33 + e];
      if (e < 16) bm[(size_t)(tok0 + tok) * 16 + e] = v;
      else        cm[(size_t)(tok0 + tok) * 16 + (e - 16)] = v;
    }
  }
}

// K3: chunk-local scan from h=0. thread = d (16 states in regs); block = (chunk, b)
__global__ __launch_bounds__(128) void k3_scan1(
    const float* __restrict__ dt, const float* __restrict__ u, const float* __restrict__ bm,
    const float* __restrict__ alog, float* __restrict__ hend, float* __restrict__ dts)
{
  const int b = blockIdx.y, ch = blockIdx.x;
  const int d = threadIdx.x;
  __shared__ float sb[TCHK][16];
  const size_t tok0 = (size_t)b * LLEN + (size_t)ch * TCHK;
  reinterpret_cast<float4*>(&sb[0][0])[d] = reinterpret_cast<const float4*>(bm + tok0 * 16)[d];
  float A[16];
  {
    const float4* ap = reinterpret_cast<const float4*>(alog + d * 16);
#pragma unroll
    for (int q = 0; q < 4; q++) {
      float4 v = ap[q];
      A[q * 4 + 0] = -__expf(v.x); A[q * 4 + 1] = -__expf(v.y);
      A[q * 4 + 2] = -__expf(v.z); A[q * 4 + 3] = -__expf(v.w);
    }
  }
  __syncthreads();
  float h[16];
#pragma unroll
  for (int s = 0; s < 16; s++) h[s] = 0.f;
  float dsum = 0.f;
  const float* dtp = dt + tok0 * DM + d;
  const float* up  = u  + tok0 * DM + d;
  for (int i = 0; i < TCHK; i++) {
    float dtv = dtp[(size_t)i * DM];
    float uv  = up[(size_t)i * DM];
    float dtu = dtv * uv;
    dsum += dtv;
    float bv[16];
#pragma unroll
    for (int q = 0; q < 4; q++)
      *reinterpret_cast<float4*>(&bv[q * 4]) = *reinterpret_cast<const float4*>(&sb[i][q * 4]);
#pragma unroll
    for (int s = 0; s < 16; s++) {
      float da = __expf(dtv * A[s]);
      h[s] = da * h[s] + dtu * bv[s];
    }
  }
  float* hp = hend + ((size_t)(b * DM + d) * NCHK + ch) * 16;
#pragma unroll
  for (int q = 0; q < 4; q++)
    reinterpret_cast<float4*>(hp)[q] = make_float4(h[q*4], h[q*4+1], h[q*4+2], h[q*4+3]);
  dts[(size_t)(b * DM + d) * NCHK + ch] = dsum;
}

// K4a: per (bd,g): register-prefetched scan of 16 chunks from h=0.
__global__ __launch_bounds__(256) void k4a_group(
    const float* __restrict__ alog, const float* __restrict__ dts, const float* __restrict__ hend,
    float* __restrict__ hlocal, float* __restrict__ cumdt,
    float* __restrict__ gend, float* __restrict__ gdt)
{
  const int tid = blockIdx.x * 256 + threadIdx.x;  // ((bd*NGRP+g)*16+s)
  const int s = tid & 15;
  const int bdg = tid >> 4;
  const int g = bdg & (NGRP - 1);
  const int bd = bdg >> 5;
  const int d = bd & (DM - 1);
  const float A = -__expf(alog[d * 16 + s]);
  const int ch0 = g * JG;
  const float* hp = hend + ((size_t)bd * NCHK + ch0) * 16 + s;
  const float* dp = dts + (size_t)bd * NCHK + ch0;
  float* hl = hlocal + ((size_t)bd * NCHK + ch0) * 16 + s;
  float hb[JG], db[JG];
#pragma unroll
  for (int j = 0; j < JG; j++) { hb[j] = hp[j * 16]; db[j] = dp[j]; }
  float h = 0.f, cd = 0.f;
#pragma unroll
  for (int j = 0; j < JG; j++) {
    hl[j * 16] = h;
    if (s == 0) cumdt[(size_t)(ch0 + j) * (BB * DM) + bd] = cd;
    h = __expf(A * db[j]) * h + hb[j];
    cd += db[j];
  }
  gend[(size_t)bdg * 16 + s] = h;
  if (s == 0) gdt[bdg] = cd;
}

// K4b: serial combine over 32 group summaries per chain (register-prefetched)
__global__ __launch_bounds__(64) void k4b_combine(
    const float* __restrict__ alog, const float* __restrict__ gdt, const float* __restrict__ gend,
    float* __restrict__ ginit)
{
  const int tid = blockIdx.x * 64 + threadIdx.x;   // bd*16+s
  const int s = tid & 15, bd = tid >> 4, d = bd & (DM - 1);
  const float A = -__expf(alog[d * 16 + s]);
  const float* ge = gend + (size_t)bd * NGRP * 16 + s;
  const float* gd = gdt + (size_t)bd * NGRP;
  float* gi = ginit + (size_t)bd * NGRP * 16 + s;
  float gb[NGRP], db[NGRP];
#pragma unroll
  for (int g = 0; g < NGRP; g++) { gb[g] = ge[g * 16]; db[g] = gd[g]; }
  float h = 0.f;
#pragma unroll
  for (int g = 0; g < NGRP; g++) {
    gi[g * 16] = h;
    h = __expf(A * db[g]) * h + gb[g];
  }
}

// K5: reconstruct h_init = exp(A*cumdt)*ginit + hlocal, then re-scan;
// y = (sum_s h*C + u*D)*silu(z), written in-place over dt
__global__ __launch_bounds__(128) void k5_scan2(
    float* __restrict__ dty, const float* __restrict__ u, const float* __restrict__ bm,
    const float* __restrict__ cm, const float* __restrict__ alog, const float* __restrict__ Dv,
    const float* __restrict__ z, const float* __restrict__ hlocal,
    const float* __restrict__ cumdt, const float* __restrict__ ginit)
{
  const int b = blockIdx.y, ch = blockIdx.x;
  const int d = threadIdx.x;
  __shared__ float sb[TCHK][16], sc[TCHK][16];
  const size_t tok0 = (size_t)b * LLEN + (size_t)ch * TCHK;
  reinterpret_cast<float4*>(&sb[0][0])[d] = reinterpret_cast<const float4*>(bm + tok0 * 16)[d];
  reinterpret_cast<float4*>(&sc[0][0])[d] = reinterpret_cast<const float4*>(cm + tok0 * 16)[d];
  float A[16];
  {
    const float4* ap = reinterpret_cast<const float4*>(alog + d * 16);
#pragma unroll
    for (int q = 0; q < 4; q++) {
      float4 v = ap[q];
      A[q * 4 + 0] = -__expf(v.x); A[q * 4 + 1] = -__expf(v.y);
      A[q * 4 + 2] = -__expf(v.z); A[q * 4 + 3] = -__expf(v.w);
    }
  }
  const float Dd = Dv[d];
  const int bd = b * DM + d;
  const int g = ch / JG;
  const float cd = cumdt[(size_t)ch * (BB * DM) + bd];
  float h[16];
  {
    const float4* hlp = reinterpret_cast<const float4*>(hlocal + ((size_t)bd * NCHK + ch) * 16);
    const float4* gip = reinterpret_cast<const float4*>(ginit + ((size_t)(bd * NGRP + g)) * 16);
#pragma unroll
    for (int q = 0; q < 4; q++) {
      float4 hl = hlp[q];
      float4 gi = gip[q];
      h[q * 4 + 0] = __expf(A[q * 4 + 0] * cd) * gi.x + hl.x;
      h[q * 4 + 1] = __expf(A[q * 4 + 1] * cd) * gi.y + hl.y;
      h[q * 4 + 2] = __expf(A[q * 4 + 2] * cd) * gi.z + hl.z;
      h[q * 4 + 3] = __expf(A[q * 4 + 3] * cd) * gi.w + hl.w;
    }
  }
  __syncthreads();
  float* dtp = dty + tok0 * DM + d;
  const float* up = u + tok0 * DM + d;
  const float* zp = z + tok0 * DM + d;
  for (int i = 0; i < TCHK; i++) {
    float dtv = dtp[(size_t)i * DM];
    float uv  = up[(size_t)i * DM];
    float zv  = zp[(size_t)i * DM];
    float dtu = dtv * uv;
    float bv[16], cv[16];
#pragma unroll
    for (int q = 0; q < 4; q++) {
      *reinterpret_cast<float4*>(&bv[q * 4]) = *reinterpret_cast<const float4*>(&sb[i][q * 4]);
      *reinterpret_cast<float4*>(&cv[q * 4]) = *reinterpret_cast<const float4*>(&sc[i][q * 4]);
    }
    float y = 0.f;
#pragma unroll
    for (int s = 0; s < 16; s++) {
      float da = __expf(dtv * A[s]);
      h[s] = da * h[s] + dtu * bv[s];
      y += h[s] * cv[s];
    }
    y = (y + uv * Dd) * fsilu(zv);
    dtp[(size_t)i * DM] = y;
  }
}

// K6: out = y @ out_proj_w^T + per-(b,group) partial GN stats
__global__ __launch_bounds__(256) void k6_outproj(
    const float* __restrict__ yv, const float* __restrict__ ow,
    float* __restrict__ ym, float* __restrict__ stat)
{
  const int b = blockIdx.y;
  const int l0 = blockIdx.x * 64;
  const int t = threadIdx.x;
  const int tm = (t & 15) * 4;
  const int tn = (t >> 4) * 4;
  __shared__ float As[64][65];
  __shared__ float Bs[64][65];
  float acc[4][4] = {};
  for (int kb = 0; kb < 2; kb++) {
#pragma unroll
    for (int i = 0; i < 16; i++) {
      int idx = t + i * 256;
      int tok = idx >> 6, dl2 = idx & 63;
      As[dl2][tok] = yv[(size_t)(b * LLEN + l0 + tok) * DM + kb * 64 + dl2];
    }
#pragma unroll
    for (int i = 0; i < 16; i++) {
      int idx = t + i * 256;
      int c = idx >> 6, dl2 = idx & 63;
      Bs[dl2][c] = ow[c * DM + kb * 64 + dl2];
    }
    __syncthreads();
    for (int dl2 = 0; dl2 < 64; dl2++) {
      float a0 = As[dl2][tm + 0], a1 = As[dl2][tm + 1], a2 = As[dl2][tm + 2], a3 = As[dl2][tm + 3];
      float b0 = Bs[dl2][tn + 0], b1 = Bs[dl2][tn + 1], b2 = Bs[dl2][tn + 2], b3 = Bs[dl2][tn + 3];
      acc[0][0] += a0 * b0; acc[0][1] += a0 * b1; acc[0][2] += a0 * b2; acc[0][3] += a0 * b3;
      acc[1][0] += a1 * b0; acc[1][1] += a1 * b1; acc[1][2] += a1 * b2; acc[1][3] += a1 * b3;
      acc[2][0] += a2 * b0; acc[2][1] += a2 * b1; acc[2][2] += a2 * b2; acc[2][3] += a2 * b3;
      acc[3][0] += a3 * b0; acc[3][1] += a3 * b1; acc[3][2] += a3 * b2; acc[3][3] += a3 * b3;
    }
    __syncthreads();
  }
  float lsum = 0.f, lssq = 0.f;
#pragma unroll
  for (int i = 0; i < 4; i++) {
    int l = l0 + tm + i;
    float4 v = make_float4(acc[i][0], acc[i][1], acc[i][2], acc[i][3]);
    *reinterpret_cast<float4*>(ym + (size_t)(b * LLEN + l) * 64 + tn) = v;
    lsum += v.x + v.y + v.z + v.w;
    lssq += v.x * v.x + v.y * v.y + v.z * v.z + v.w * v.w;
  }
  __shared__ float sg[NG * 2];
  if (t < NG * 2) sg[t] = 0.f;
  __syncthreads();
  const int g = tn >> 4;
  atomicAdd(&sg[g * 2 + 0], lsum);
  atomicAdd(&sg[g * 2 + 1], lssq);
  __syncthreads();
  if (t < NG * 2) atomicAdd(&stat[b * NG * 2 + t], sg[t]);
}

// K7: GroupNorm finalize + silu + residual, transpose (b,l,c)->(b,c,l)
__global__ __launch_bounds__(256) void k7_gn(
    const float* __restrict__ ym, const float* __restrict__ stat,
    const float* __restrict__ scale, const float* __restrict__ bias,
    const float* __restrict__ x, float* __restrict__ out)
{
  const int b = blockIdx.y;
  const int p0 = blockIdx.x * 64;
  const int t = threadIdx.x;
  __shared__ float Ts[64][65];
#pragma unroll
  for (int i = 0; i < 16; i++) {
    int idx = t + i * 256;
    int p = idx >> 6, c = idx & 63;
    Ts[c][p] = ym[(size_t)(b * LLEN + p0 + p) * 64 + c];
  }
  __syncthreads();
  const float invN = 1.f / (16.f * 16384.f);
#pragma unroll
  for (int i = 0; i < 16; i++) {
    int idx = t + i * 256;
    int c = idx >> 6, p = idx & 63;
    int g = c >> 4;
    float mu = stat[b * 8 + g * 2] * invN;
    float var = stat[b * 8 + g * 2 + 1] * invN - mu * mu;
    float rs = rsqrtf(var + 1e-5f);
    float v = (Ts[c][p] - mu) * rs * scale[c] + bias[c];
    size_t o = (size_t)(b * CCH + c) * LLEN + p0 + p;
    out[o] = fsilu(v) + x[o];
  }
}

extern "C" void kernel_launch(void* const* d_in, const int* in_sizes, int n_in,
                              void* d_out, int out_size, void* d_ws, size_t ws_size,
                              hipStream_t stream)
{
  const float* x    = (const float*)d_in[0];
  const float* ipw  = (const float*)d_in[1];
  const float* cw   = (const float*)d_in[2];
  const float* cb   = (const float*)d_in[3];
  const float* xpw  = (const float*)d_in[4];
  const float* dtw  = (const float*)d_in[5];
  const float* dtpb = (const float*)d_in[6];
  const float* alog = (const float*)d_in[7];
  const float* Dv   = (const float*)d_in[8];
  const float* ow   = (const float*)d_in[9];
  const float* gns  = (const float*)d_in[10];
  const float* gnb  = (const float*)d_in[11];

  float* ws    = (float*)d_ws;
  float* xc    = ws + OFF_XC;
  float* hend  = ws + OFF_HEND;   // aliases xc (dead after k2)
  float* hloc  = ws + OFF_HLOC;
  float* z     = ws + OFF_Z;
  float* u     = ws + OFF_U;
  float* dt    = ws + OFF_DT;     // k5 overwrites with y in-place
  float* bm    = ws + OFF_BM;
  float* cm    = ws + OFF_CM;
  float* dts   = ws + OFF_DTS;
  float* ym    = ws + OFF_YM;
  float* wc    = ws + OFF_WC;     // aliases ym (dead until k6)
  float* cumdt = ws + OFF_CUMDT;
  float* gend  = ws + OFF_GEND;
  float* gdt   = ws + OFF_GDT;
  float* ginit = ws + OFF_GINIT;
  float* stat  = ws + OFF_STAT;
  float* out   = (float*)d_out;

  hipMemsetAsync(stat, 0, 16 * sizeof(float), stream);
  k0_wcomb<<<dim3(80), 256, 0, stream>>>(xpw, dtw, wc);
  k1_inproj<<<dim3(LLEN / 64, 4, BB), 256, 0, stream>>>(x, ipw, xc, z);
  k2a_conv<<<dim3(BB * LLEN / 64), 256, 0, stream>>>(xc, cw, cb, u);
  k2b_proj<<<dim3(BB * LLEN / 64, 5), 128, 0, stream>>>(u, wc, dtpb, dt, bm, cm);
  k3_scan1<<<dim3(NCHK, BB), 128, 0, stream>>>(dt, u, bm, alog, hend, dts);
  k4a_group<<<dim3(BB * DM * NGRP * 16 / 256), 256, 0, stream>>>(alog, dts, hend, hloc, cumdt, gend, gdt);
  k4b_combine<<<dim3(BB * DM * 16 / 64), 64, 0, stream>>>(alog, gdt, gend, ginit);
  k5_scan2<<<dim3(NCHK, BB), 128, 0, stream>>>(dt, u, bm, cm, alog, Dv, z, hloc, cumdt, ginit);
  k6_outproj<<<dim3(LLEN / 64, BB), 256, 0, stream>>>(dt, ow, ym, stat);
  k7_gn<<<dim3(LLEN / 64, BB), 256, 0, stream>>>(ym, stat, gns, gnb, x, out);
}

// Round 9
// 151.249 us; speedup vs baseline: 1.1692x; 1.1692x over previous
//
#include <hip/hip_runtime.h>

#define BB 2
#define CCH 64
#define LLEN 16384
#define DM 128
#define NCHK 512
#define TCHK 32
#define NGRP 32
#define JG 16
#define NG 4

// workspace offsets (floats). hend aliases xc (dead after k2); hlocal in old hin slot;
// y overwrites dt in k5. wc + k4 small buffers alias ym (dead until k6).
#define OFF_XC   0ull
#define OFF_HEND 0ull
#define OFF_HLOC 2097152ull
#define OFF_Z    4194304ull
#define OFF_U    8388608ull
#define OFF_DT   12582912ull
#define OFF_BM   16777216ull
#define OFF_CM   17301504ull
#define OFF_DTS  17825792ull
#define OFF_YM   17956864ull
#define OFF_WC   17956864ull
#define OFF_CUMDT (17956864ull + 450000ull)
#define OFF_GEND  (OFF_CUMDT + 131072ull)
#define OFF_GDT   (OFF_GEND + 131072ull)
#define OFF_GINIT (OFF_GDT + 8192ull)
#define OFF_STAT 20054016ull

__device__ __forceinline__ float fsilu(float v) {
  return v * __builtin_amdgcn_rcpf(1.f + __expf(-v));
}
__device__ __forceinline__ float fsoftplus(float v) {
  return v > 20.f ? v : __logf(1.f + __expf(v));
}

// K1: xz = xr @ in_proj_w^T ; split into xc (e<128) and z (e>=128)
// LDS rows padded to 68 floats (16B-aligned) -> ds_read_b128 in the hot loop.
__global__ __launch_bounds__(256) void k1_inproj(
    const float* __restrict__ x, const float* __restrict__ w,
    float* __restrict__ xc, float* __restrict__ z)
{
  const int b = blockIdx.z;
  const int l0 = blockIdx.x * 64;
  const int e0 = blockIdx.y * 64;
  __shared__ float As[64][68];  // [c][tok]
  __shared__ float Bs[64][68];  // [c][e]
  const int t = threadIdx.x;
  // A staging: float4 copy, no transpose (x is [c][l], As is [c][tok])
#pragma unroll
  for (int i = 0; i < 4; i++) {
    int f4 = t + i * 256;                 // 1024 float4s
    int c = f4 >> 4, tok4 = (f4 & 15) * 4;
    *reinterpret_cast<float4*>(&As[c][tok4]) =
        *reinterpret_cast<const float4*>(&x[(size_t)(b * CCH + c) * LLEN + l0 + tok4]);
  }
  // B staging: scalar transpose (one-time; 8-way write conflict acceptable)
#pragma unroll
  for (int i = 0; i < 16; i++) {
    int idx = t + i * 256;
    int e = idx >> 6, c = idx & 63;
    Bs[c][e] = w[(e0 + e) * CCH + c];
  }
  __syncthreads();
  const int tm = (t & 15) * 4;
  const int tn = (t >> 4) * 4;
  float acc[4][4] = {};
  for (int c = 0; c < 64; c++) {
    float4 av = *reinterpret_cast<const float4*>(&As[c][tm]);
    float4 bv = *reinterpret_cast<const float4*>(&Bs[c][tn]);
    acc[0][0] += av.x * bv.x; acc[0][1] += av.x * bv.y; acc[0][2] += av.x * bv.z; acc[0][3] += av.x * bv.w;
    acc[1][0] += av.y * bv.x; acc[1][1] += av.y * bv.y; acc[1][2] += av.y * bv.z; acc[1][3] += av.y * bv.w;
    acc[2][0] += av.z * bv.x; acc[2][1] += av.z * bv.y; acc[2][2] += av.z * bv.z; acc[2][3] += av.z * bv.w;
    acc[3][0] += av.w * bv.x; acc[3][1] += av.w * bv.y; acc[3][2] += av.w * bv.z; acc[3][3] += av.w * bv.w;
  }
  float* dst = (e0 < DM) ? (xc + e0) : (z + (e0 - DM));
#pragma unroll
  for (int i = 0; i < 4; i++) {
    int l = l0 + tm + i;
    float4 v = make_float4(acc[i][0], acc[i][1], acc[i][2], acc[i][3]);
    *reinterpret_cast<float4*>(dst + (size_t)(b * LLEN + l) * DM + tn) = v;
  }
}

// K0: W_comb[160][128]: rows 0..127 = dtw @ xpw[0:4]; rows 128..159 = xpw[4:36]
__global__ __launch_bounds__(256) void k0_wcomb(
    const float* __restrict__ xpw, const float* __restrict__ dtw, float* __restrict__ wc)
{
  int i = blockIdx.x * 256 + threadIdx.x;
  if (i >= 160 * 128) return;
  int e = i >> 7, dd = i & 127;
  float v;
  if (e < 128) {
    v = dtw[e * 4 + 0] * xpw[0 * 128 + dd] + dtw[e * 4 + 1] * xpw[1 * 128 + dd]
      + dtw[e * 4 + 2] * xpw[2 * 128 + dd] + dtw[e * 4 + 3] * xpw[3 * 128 + dd];
  } else {
    v = xpw[(e - 128 + 4) * 128 + dd];
  }
  wc[i] = v;
}

// K2a: u = silu(causal_conv4(xc) + cb). Block = 64 tokens x 128 d; thread = 8 tok x 4 d.
__global__ __launch_bounds__(256) void k2a_conv(
    const float* __restrict__ xc, const float* __restrict__ cw, const float* __restrict__ cb,
    float* __restrict__ u)
{
  const int t = threadIdx.x;
  const int d4 = (t & 31) * 4;
  const int tg = t >> 5;
  const int tok0 = blockIdx.x * 64 + tg * 8;
  const int l0 = tok0 & (LLEN - 1);
  float4 w0 = *reinterpret_cast<const float4*>(cw + (d4 + 0) * 4);
  float4 w1 = *reinterpret_cast<const float4*>(cw + (d4 + 1) * 4);
  float4 w2 = *reinterpret_cast<const float4*>(cw + (d4 + 2) * 4);
  float4 w3 = *reinterpret_cast<const float4*>(cw + (d4 + 3) * 4);
  float4 bias = *reinterpret_cast<const float4*>(cb + d4);
  float4 row[11];
#pragma unroll
  for (int r = 0; r < 11; r++) {
    int l = l0 - 3 + r;
    if (l < 0) row[r] = make_float4(0.f, 0.f, 0.f, 0.f);
    else row[r] = *reinterpret_cast<const float4*>(xc + (size_t)(tok0 - 3 + r) * DM + d4);
  }
#pragma unroll
  for (int j = 0; j < 8; j++) {
    float4 acc;
    acc.x = bias.x + w0.x * row[j].x + w0.y * row[j+1].x + w0.z * row[j+2].x + w0.w * row[j+3].x;
    acc.y = bias.y + w1.x * row[j].y + w1.y * row[j+1].y + w1.z * row[j+2].y + w1.w * row[j+3].y;
    acc.z = bias.z + w2.x * row[j].z + w2.y * row[j+1].z + w2.z * row[j+2].z + w2.w * row[j+3].z;
    acc.w = bias.w + w3.x * row[j].w + w3.y * row[j+1].w + w3.z * row[j+2].w + w3.w * row[j+3].w;
    acc.x = fsilu(acc.x); acc.y = fsilu(acc.y); acc.z = fsilu(acc.z); acc.w = fsilu(acc.w);
    *reinterpret_cast<float4*>(u + (size_t)(tok0 + j) * DM + d4) = acc;
  }
}

// K2b: dbc160 = u @ W_comb^T. M=BL, N=160 (5 tiles of 32), K=128 (2 passes of BK=64).
// 128 threads, micro-tile 4 tok x 4 e; aligned pads (68/36) -> b128 LDS ops;
// staging via 4x4 register transpose (float4 global loads, b128 LDS writes).
__global__ __launch_bounds__(128) void k2b_proj(
    const float* __restrict__ u, const float* __restrict__ wc, const float* __restrict__ dtpb,
    float* __restrict__ dt, float* __restrict__ bm, float* __restrict__ cm)
{
  const int tok0 = blockIdx.x * 64;
  const int e0 = blockIdx.y * 32;
  const int t = threadIdx.x;
  __shared__ float As[64][68];   // [k][tok]
  __shared__ float Bs[64][36];   // [k][e]
  const int tm = (t & 15) * 4;   // token offset
  const int tn = (t >> 4) * 4;   // e offset 0..28
  float acc[4][4] = {};
  for (int kb = 0; kb < 2; kb++) {
    // A staging: 4x4 register transpose. 256 tiles, 2 per thread.
#pragma unroll
    for (int i2 = 0; i2 < 2; i2++) {
      int tile = t + i2 * 128;
      int kt4 = (tile & 15) * 4, tok4 = (tile >> 4) * 4;
      const float* gp = u + (size_t)(tok0 + tok4) * DM + kb * 64 + kt4;
      float4 r0 = *reinterpret_cast<const float4*>(gp + 0 * DM);
      float4 r1 = *reinterpret_cast<const float4*>(gp + 1 * DM);
      float4 r2 = *reinterpret_cast<const float4*>(gp + 2 * DM);
      float4 r3 = *reinterpret_cast<const float4*>(gp + 3 * DM);
      *reinterpret_cast<float4*>(&As[kt4 + 0][tok4]) = make_float4(r0.x, r1.x, r2.x, r3.x);
      *reinterpret_cast<float4*>(&As[kt4 + 1][tok4]) = make_float4(r0.y, r1.y, r2.y, r3.y);
      *reinterpret_cast<float4*>(&As[kt4 + 2][tok4]) = make_float4(r0.z, r1.z, r2.z, r3.z);
      *reinterpret_cast<float4*>(&As[kt4 + 3][tok4]) = make_float4(r0.w, r1.w, r2.w, r3.w);
    }
    // B staging: 4x4 register transpose. 128 tiles, 1 per thread.
    {
      int kt4 = (t & 15) * 4, et4 = (t >> 4) * 4;
      const float* gp = wc + (size_t)(e0 + et4) * DM + kb * 64 + kt4;
      float4 r0 = *reinterpret_cast<const float4*>(gp + 0 * DM);
      float4 r1 = *reinterpret_cast<const float4*>(gp + 1 * DM);
      float4 r2 = *reinterpret_cast<const float4*>(gp + 2 * DM);
      float4 r3 = *reinterpret_cast<const float4*>(gp + 3 * DM);
      *reinterpret_cast<float4*>(&Bs[kt4 + 0][et4]) = make_float4(r0.x, r1.x, r2.x, r3.x);
      *reinterpret_cast<float4*>(&Bs[kt4 + 1][et4]) = make_float4(r0.y, r1.y, r2.y, r3.y);
      *reinterpret_cast<float4*>(&Bs[kt4 + 2][et4]) = make_float4(r0.z, r1.z, r2.z, r3.z);
      *reinterpret_cast<float4*>(&Bs[kt4 + 3][et4]) = make_float4(r0.w, r1.w, r2.w, r3.w);
    }
    __syncthreads();
#pragma unroll 4
    for (int k = 0; k < 64; k++) {
      float4 av = *reinterpret_cast<const float4*>(&As[k][tm]);
      float4 bv = *reinterpret_cast<const float4*>(&Bs[k][tn]);
      acc[0][0] += av.x * bv.x; acc[0][1] += av.x * bv.y; acc[0][2] += av.x * bv.z; acc[0][3] += av.x * bv.w;
      acc[1][0] += av.y * bv.x; acc[1][1] += av.y * bv.y; acc[1][2] += av.y * bv.z; acc[1][3] += av.y * bv.w;
      acc[2][0] += av.z * bv.x; acc[2][1] += av.z * bv.y; acc[2][2] += av.z * bv.z; acc[2][3] += av.z * bv.w;
      acc[3][0] += av.w * bv.x; acc[3][1] += av.w * bv.y; acc[3][2] += av.w * bv.z; acc[3][3] += av.w * bv.w;
    }
    __syncthreads();
  }
  // stage results in LDS (over As memory) for coalesced writeback: Cs[tok][e], stride 33
  float* Cs = &As[0][0];
#pragma unroll
  for (int i = 0; i < 4; i++) {
#pragma unroll
    for (int j = 0; j < 4; j++) Cs[(tm + i) * 33 + tn + j] = acc[i][j];
  }
  __syncthreads();
  if (e0 < DM) {
#pragma unroll
    for (int i = 0; i < 16; i++) {
      int idx = t + i * 128;
      int tok = idx >> 5, e = idx & 31;
      float v = fsoftplus(Cs[tok * 33 + e] + dtpb[e0 + e]);
      dt[(size_t)(tok0 + tok) * DM + e0 + e] = v;
    }
  } else {
#pragma unroll
    for (int i = 0; i < 16; i++) {
      int idx = t + i * 128;
      int tok = idx >> 5, e = idx & 31;
      float v = Cs[tok * 33 + e];
      if (e < 16) bm[(size_t)(tok0 + tok) * 16 + e] = v;
      else        cm[(size_t)(tok0 + tok) * 16 + (e - 16)] = v;
    }
  }
}

// K3: chunk-local scan from h=0. thread = d (16 states in regs); block = (chunk, b)
__global__ __launch_bounds__(128) void k3_scan1(
    const float* __restrict__ dt, const float* __restrict__ u, const float* __restrict__ bm,
    const float* __restrict__ alog, float* __restrict__ hend, float* __restrict__ dts)
{
  const int b = blockIdx.y, ch = blockIdx.x;
  const int d = threadIdx.x;
  __shared__ float sb[TCHK][16];
  const size_t tok0 = (size_t)b * LLEN + (size_t)ch * TCHK;
  reinterpret_cast<float4*>(&sb[0][0])[d] = reinterpret_cast<const float4*>(bm + tok0 * 16)[d];
  float A[16];
  {
    const float4* ap = reinterpret_cast<const float4*>(alog + d * 16);
#pragma unroll
    for (int q = 0; q < 4; q++) {
      float4 v = ap[q];
      A[q * 4 + 0] = -__expf(v.x); A[q * 4 + 1] = -__expf(v.y);
      A[q * 4 + 2] = -__expf(v.z); A[q * 4 + 3] = -__expf(v.w);
    }
  }
  __syncthreads();
  float h[16];
#pragma unroll
  for (int s = 0; s < 16; s++) h[s] = 0.f;
  float dsum = 0.f;
  const float* dtp = dt + tok0 * DM + d;
  const float* up  = u  + tok0 * DM + d;
  for (int i = 0; i < TCHK; i++) {
    float dtv = dtp[(size_t)i * DM];
    float uv  = up[(size_t)i * DM];
    float dtu = dtv * uv;
    dsum += dtv;
    float bv[16];
#pragma unroll
    for (int q = 0; q < 4; q++)
      *reinterpret_cast<float4*>(&bv[q * 4]) = *reinterpret_cast<const float4*>(&sb[i][q * 4]);
#pragma unroll
    for (int s = 0; s < 16; s++) {
      float da = __expf(dtv * A[s]);
      h[s] = da * h[s] + dtu * bv[s];
    }
  }
  float* hp = hend + ((size_t)(b * DM + d) * NCHK + ch) * 16;
#pragma unroll
  for (int q = 0; q < 4; q++)
    reinterpret_cast<float4*>(hp)[q] = make_float4(h[q*4], h[q*4+1], h[q*4+2], h[q*4+3]);
  dts[(size_t)(b * DM + d) * NCHK + ch] = dsum;
}

// K4a: per (bd,g): register-prefetched scan of 16 chunks from h=0.
__global__ __launch_bounds__(256) void k4a_group(
    const float* __restrict__ alog, const float* __restrict__ dts, const float* __restrict__ hend,
    float* __restrict__ hlocal, float* __restrict__ cumdt,
    float* __restrict__ gend, float* __restrict__ gdt)
{
  const int tid = blockIdx.x * 256 + threadIdx.x;  // ((bd*NGRP+g)*16+s)
  const int s = tid & 15;
  const int bdg = tid >> 4;
  const int g = bdg & (NGRP - 1);
  const int bd = bdg >> 5;
  const int d = bd & (DM - 1);
  const float A = -__expf(alog[d * 16 + s]);
  const int ch0 = g * JG;
  const float* hp = hend + ((size_t)bd * NCHK + ch0) * 16 + s;
  const float* dp = dts + (size_t)bd * NCHK + ch0;
  float* hl = hlocal + ((size_t)bd * NCHK + ch0) * 16 + s;
  float hb[JG], db[JG];
#pragma unroll
  for (int j = 0; j < JG; j++) { hb[j] = hp[j * 16]; db[j] = dp[j]; }
  float h = 0.f, cd = 0.f;
#pragma unroll
  for (int j = 0; j < JG; j++) {
    hl[j * 16] = h;
    if (s == 0) cumdt[(size_t)(ch0 + j) * (BB * DM) + bd] = cd;
    h = __expf(A * db[j]) * h + hb[j];
    cd += db[j];
  }
  gend[(size_t)bdg * 16 + s] = h;
  if (s == 0) gdt[bdg] = cd;
}

// K4b: serial combine over 32 group summaries per chain (register-prefetched)
__global__ __launch_bounds__(64) void k4b_combine(
    const float* __restrict__ alog, const float* __restrict__ gdt, const float* __restrict__ gend,
    float* __restrict__ ginit)
{
  const int tid = blockIdx.x * 64 + threadIdx.x;   // bd*16+s
  const int s = tid & 15, bd = tid >> 4, d = bd & (DM - 1);
  const float A = -__expf(alog[d * 16 + s]);
  const float* ge = gend + (size_t)bd * NGRP * 16 + s;
  const float* gd = gdt + (size_t)bd * NGRP;
  float* gi = ginit + (size_t)bd * NGRP * 16 + s;
  float gb[NGRP], db[NGRP];
#pragma unroll
  for (int g = 0; g < NGRP; g++) { gb[g] = ge[g * 16]; db[g] = gd[g]; }
  float h = 0.f;
#pragma unroll
  for (int g = 0; g < NGRP; g++) {
    gi[g * 16] = h;
    h = __expf(A * db[g]) * h + gb[g];
  }
}

// K5: reconstruct h_init = exp(A*cumdt)*ginit + hlocal, then re-scan;
// y = (sum_s h*C + u*D)*silu(z), written in-place over dt
__global__ __launch_bounds__(128) void k5_scan2(
    float* __restrict__ dty, const float* __restrict__ u, const float* __restrict__ bm,
    const float* __restrict__ cm, const float* __restrict__ alog, const float* __restrict__ Dv,
    const float* __restrict__ z, const float* __restrict__ hlocal,
    const float* __restrict__ cumdt, const float* __restrict__ ginit)
{
  const int b = blockIdx.y, ch = blockIdx.x;
  const int d = threadIdx.x;
  __shared__ float sb[TCHK][16], sc[TCHK][16];
  const size_t tok0 = (size_t)b * LLEN + (size_t)ch * TCHK;
  reinterpret_cast<float4*>(&sb[0][0])[d] = reinterpret_cast<const float4*>(bm + tok0 * 16)[d];
  reinterpret_cast<float4*>(&sc[0][0])[d] = reinterpret_cast<const float4*>(cm + tok0 * 16)[d];
  float A[16];
  {
    const float4* ap = reinterpret_cast<const float4*>(alog + d * 16);
#pragma unroll
    for (int q = 0; q < 4; q++) {
      float4 v = ap[q];
      A[q * 4 + 0] = -__expf(v.x); A[q * 4 + 1] = -__expf(v.y);
      A[q * 4 + 2] = -__expf(v.z); A[q * 4 + 3] = -__expf(v.w);
    }
  }
  const float Dd = Dv[d];
  const int bd = b * DM + d;
  const int g = ch / JG;
  const float cd = cumdt[(size_t)ch * (BB * DM) + bd];
  float h[16];
  {
    const float4* hlp = reinterpret_cast<const float4*>(hlocal + ((size_t)bd * NCHK + ch) * 16);
    const float4* gip = reinterpret_cast<const float4*>(ginit + ((size_t)(bd * NGRP + g)) * 16);
#pragma unroll
    for (int q = 0; q < 4; q++) {
      float4 hl = hlp[q];
      float4 gi = gip[q];
      h[q * 4 + 0] = __expf(A[q * 4 + 0] * cd) * gi.x + hl.x;
      h[q * 4 + 1] = __expf(A[q * 4 + 1] * cd) * gi.y + hl.y;
      h[q * 4 + 2] = __expf(A[q * 4 + 2] * cd) * gi.z + hl.z;
      h[q * 4 + 3] = __expf(A[q * 4 + 3] * cd) * gi.w + hl.w;
    }
  }
  __syncthreads();
  float* dtp = dty + tok0 * DM + d;
  const float* up = u + tok0 * DM + d;
  const float* zp = z + tok0 * DM + d;
  for (int i = 0; i < TCHK; i++) {
    float dtv = dtp[(size_t)i * DM];
    float uv  = up[(size_t)i * DM];
    float zv  = zp[(size_t)i * DM];
    float dtu = dtv * uv;
    float bv[16], cv[16];
#pragma unroll
    for (int q = 0; q < 4; q++) {
      *reinterpret_cast<float4*>(&bv[q * 4]) = *reinterpret_cast<const float4*>(&sb[i][q * 4]);
      *reinterpret_cast<float4*>(&cv[q * 4]) = *reinterpret_cast<const float4*>(&sc[i][q * 4]);
    }
    float y = 0.f;
#pragma unroll
    for (int s = 0; s < 16; s++) {
      float da = __expf(dtv * A[s]);
      h[s] = da * h[s] + dtu * bv[s];
      y += h[s] * cv[s];
    }
    y = (y + uv * Dd) * fsilu(zv);
    dtp[(size_t)i * DM] = y;
  }
}

// K6: out = y @ out_proj_w^T + per-(b,group) partial GN stats.
// Aligned pad 68 + 4x4 register-transpose A staging -> b128 LDS ops.
__global__ __launch_bounds__(256) void k6_outproj(
    const float* __restrict__ yv, const float* __restrict__ ow,
    float* __restrict__ ym, float* __restrict__ stat)
{
  const int b = blockIdx.y;
  const int l0 = blockIdx.x * 64;
  const int t = threadIdx.x;
  const int tm = (t & 15) * 4;
  const int tn = (t >> 4) * 4;
  __shared__ float As[64][68];  // [dl][tok]
  __shared__ float Bs[64][68];  // [dl][c]
  float acc[4][4] = {};
  for (int kb = 0; kb < 2; kb++) {
    // A staging: 4x4 register transpose (256 tiles, 1 per thread)
    {
      int dl4 = (t & 15) * 4, tok4 = (t >> 4) * 4;
      const float* gp = yv + (size_t)(b * LLEN + l0 + tok4) * DM + kb * 64 + dl4;
      float4 r0 = *reinterpret_cast<const float4*>(gp + 0 * DM);
      float4 r1 = *reinterpret_cast<const float4*>(gp + 1 * DM);
      float4 r2 = *reinterpret_cast<const float4*>(gp + 2 * DM);
      float4 r3 = *reinterpret_cast<const float4*>(gp + 3 * DM);
      *reinterpret_cast<float4*>(&As[dl4 + 0][tok4]) = make_float4(r0.x, r1.x, r2.x, r3.x);
      *reinterpret_cast<float4*>(&As[dl4 + 1][tok4]) = make_float4(r0.y, r1.y, r2.y, r3.y);
      *reinterpret_cast<float4*>(&As[dl4 + 2][tok4]) = make_float4(r0.z, r1.z, r2.z, r3.z);
      *reinterpret_cast<float4*>(&As[dl4 + 3][tok4]) = make_float4(r0.w, r1.w, r2.w, r3.w);
    }
    // B staging: scalar transpose (one-time)
#pragma unroll
    for (int i = 0; i < 16; i++) {
      int idx = t + i * 256;
      int c = idx >> 6, dl2 = idx & 63;
      Bs[dl2][c] = ow[c * DM + kb * 64 + dl2];
    }
    __syncthreads();
    for (int dl2 = 0; dl2 < 64; dl2++) {
      float4 av = *reinterpret_cast<const float4*>(&As[dl2][tm]);
      float4 bv = *reinterpret_cast<const float4*>(&Bs[dl2][tn]);
      acc[0][0] += av.x * bv.x; acc[0][1] += av.x * bv.y; acc[0][2] += av.x * bv.z; acc[0][3] += av.x * bv.w;
      acc[1][0] += av.y * bv.x; acc[1][1] += av.y * bv.y; acc[1][2] += av.y * bv.z; acc[1][3] += av.y * bv.w;
      acc[2][0] += av.z * bv.x; acc[2][1] += av.z * bv.y; acc[2][2] += av.z * bv.z; acc[2][3] += av.z * bv.w;
      acc[3][0] += av.w * bv.x; acc[3][1] += av.w * bv.y; acc[3][2] += av.w * bv.z; acc[3][3] += av.w * bv.w;
    }
    __syncthreads();
  }
  float lsum = 0.f, lssq = 0.f;
#pragma unroll
  for (int i = 0; i < 4; i++) {
    int l = l0 + tm + i;
    float4 v = make_float4(acc[i][0], acc[i][1], acc[i][2], acc[i][3]);
    *reinterpret_cast<float4*>(ym + (size_t)(b * LLEN + l) * 64 + tn) = v;
    lsum += v.x + v.y + v.z + v.w;
    lssq += v.x * v.x + v.y * v.y + v.z * v.z + v.w * v.w;
  }
  __shared__ float sg[NG * 2];
  if (t < NG * 2) sg[t] = 0.f;
  __syncthreads();
  const int g = tn >> 4;
  atomicAdd(&sg[g * 2 + 0], lsum);
  atomicAdd(&sg[g * 2 + 1], lssq);
  __syncthreads();
  if (t < NG * 2) atomicAdd(&stat[b * NG * 2 + t], sg[t]);
}

// K7: GroupNorm finalize + silu + residual, transpose (b,l,c)->(b,c,l)
__global__ __launch_bounds__(256) void k7_gn(
    const float* __restrict__ ym, const float* __restrict__ stat,
    const float* __restrict__ scale, const float* __restrict__ bias,
    const float* __restrict__ x, float* __restrict__ out)
{
  const int b = blockIdx.y;
  const int p0 = blockIdx.x * 64;
  const int t = threadIdx.x;
  __shared__ float Ts[64][65];
#pragma unroll
  for (int i = 0; i < 16; i++) {
    int idx = t + i * 256;
    int p = idx >> 6, c = idx & 63;
    Ts[c][p] = ym[(size_t)(b * LLEN + p0 + p) * 64 + c];
  }
  __syncthreads();
  const float invN = 1.f / (16.f * 16384.f);
#pragma unroll
  for (int i = 0; i < 16; i++) {
    int idx = t + i * 256;
    int c = idx >> 6, p = idx & 63;
    int g = c >> 4;
    float mu = stat[b * 8 + g * 2] * invN;
    float var = stat[b * 8 + g * 2 + 1] * invN - mu * mu;
    float rs = rsqrtf(var + 1e-5f);
    float v = (Ts[c][p] - mu) * rs * scale[c] + bias[c];
    size_t o = (size_t)(b * CCH + c) * LLEN + p0 + p;
    out[o] = fsilu(v) + x[o];
  }
}

extern "C" void kernel_launch(void* const* d_in, const int* in_sizes, int n_in,
                              void* d_out, int out_size, void* d_ws, size_t ws_size,
                              hipStream_t stream)
{
  const float* x    = (const float*)d_in[0];
  const float* ipw  = (const float*)d_in[1];
  const float* cw   = (const float*)d_in[2];
  const float* cb   = (const float*)d_in[3];
  const float* xpw  = (const float*)d_in[4];
  const float* dtw  = (const float*)d_in[5];
  const float* dtpb = (const float*)d_in[6];
  const float* alog = (const float*)d_in[7];
  const float* Dv   = (const float*)d_in[8];
  const float* ow   = (const float*)d_in[9];
  const float* gns  = (const float*)d_in[10];
  const float* gnb  = (const float*)d_in[11];

  float* ws    = (float*)d_ws;
  float* xc    = ws + OFF_XC;
  float* hend  = ws + OFF_HEND;
  float* hloc  = ws + OFF_HLOC;
  float* z     = ws + OFF_Z;
  float* u     = ws + OFF_U;
  float* dt    = ws + OFF_DT;
  float* bm    = ws + OFF_BM;
  float* cm    = ws + OFF_CM;
  float* dts   = ws + OFF_DTS;
  float* ym    = ws + OFF_YM;
  float* wc    = ws + OFF_WC;
  float* cumdt = ws + OFF_CUMDT;
  float* gend  = ws + OFF_GEND;
  float* gdt   = ws + OFF_GDT;
  float* ginit = ws + OFF_GINIT;
  float* stat  = ws + OFF_STAT;
  float* out   = (float*)d_out;

  hipMemsetAsync(stat, 0, 16 * sizeof(float), stream);
  k0_wcomb<<<dim3(80), 256, 0, stream>>>(xpw, dtw, wc);
  k1_inproj<<<dim3(LLEN / 64, 4, BB), 256, 0, stream>>>(x, ipw, xc, z);
  k2a_conv<<<dim3(BB * LLEN / 64), 256, 0, stream>>>(xc, cw, cb, u);
  k2b_proj<<<dim3(BB * LLEN / 64, 5), 128, 0, stream>>>(u, wc, dtpb, dt, bm, cm);
  k3_scan1<<<dim3(NCHK, BB), 128, 0, stream>>>(dt, u, bm, alog, hend, dts);
  k4a_group<<<dim3(BB * DM * NGRP * 16 / 256), 256, 0, stream>>>(alog, dts, hend, hloc, cumdt, gend, gdt);
  k4b_combine<<<dim3(BB * DM * 16 / 64), 64, 0, stream>>>(alog, gdt, gend, ginit);
  k5_scan2<<<dim3(NCHK, BB), 128, 0, stream>>>(dt, u, bm, cm, alog, Dv, z, hloc, cumdt, ginit);
  k6_outproj<<<dim3(LLEN / 64, BB), 256, 0, stream>>>(dt, ow, ym, stat);
  k7_gn<<<dim3(LLEN / 64, BB), 256, 0, stream>>>(ym, stat, gns, gnb, x, out);
}

// Round 10
// 149.562 us; speedup vs baseline: 1.1824x; 1.0113x over previous
//
#include <hip/hip_runtime.h>

#define BB 2
#define CCH 64
#define LLEN 16384
#define DM 128
#define NCHK 512
#define TCHK 32
#define NGRP 32
#define JG 16
#define NG 4

// workspace offsets (floats). hend aliases xc (dead after k2); hlocal in old hin slot;
// y overwrites dt in k5. wc + k4 small buffers alias ym (dead until k6).
#define OFF_XC   0ull
#define OFF_HEND 0ull
#define OFF_HLOC 2097152ull
#define OFF_Z    4194304ull
#define OFF_U    8388608ull
#define OFF_DT   12582912ull
#define OFF_BM   16777216ull
#define OFF_CM   17301504ull
#define OFF_DTS  17825792ull
#define OFF_YM   17956864ull
#define OFF_WC   17956864ull
#define OFF_CUMDT (17956864ull + 450000ull)
#define OFF_GEND  (OFF_CUMDT + 131072ull)
#define OFF_GDT   (OFF_GEND + 131072ull)
#define OFF_GINIT (OFF_GDT + 8192ull)
#define OFF_STAT 20054016ull

__device__ __forceinline__ float fsilu(float v) {
  return v * __builtin_amdgcn_rcpf(1.f + __expf(-v));
}
__device__ __forceinline__ float fsoftplus(float v) {
  return v > 20.f ? v : __logf(1.f + __expf(v));
}

// K1: xz = xr @ in_proj_w^T ; split into xc (e<128) and z (e>=128)
// LDS rows padded to 68 floats (16B-aligned) -> ds_read_b128 in the hot loop.
__global__ __launch_bounds__(256) void k1_inproj(
    const float* __restrict__ x, const float* __restrict__ w,
    float* __restrict__ xc, float* __restrict__ z)
{
  const int b = blockIdx.z;
  const int l0 = blockIdx.x * 64;
  const int e0 = blockIdx.y * 64;
  __shared__ float As[64][68];  // [c][tok]
  __shared__ float Bs[64][68];  // [c][e]
  const int t = threadIdx.x;
  // A staging: float4 copy, no transpose (x is [c][l], As is [c][tok])
#pragma unroll
  for (int i = 0; i < 4; i++) {
    int f4 = t + i * 256;                 // 1024 float4s
    int c = f4 >> 4, tok4 = (f4 & 15) * 4;
    *reinterpret_cast<float4*>(&As[c][tok4]) =
        *reinterpret_cast<const float4*>(&x[(size_t)(b * CCH + c) * LLEN + l0 + tok4]);
  }
  // B staging: scalar transpose (one-time; write conflicts acceptable)
#pragma unroll
  for (int i = 0; i < 16; i++) {
    int idx = t + i * 256;
    int e = idx >> 6, c = idx & 63;
    Bs[c][e] = w[(e0 + e) * CCH + c];
  }
  __syncthreads();
  const int tm = (t & 15) * 4;
  const int tn = (t >> 4) * 4;
  float acc[4][4] = {};
  for (int c = 0; c < 64; c++) {
    float4 av = *reinterpret_cast<const float4*>(&As[c][tm]);
    float4 bv = *reinterpret_cast<const float4*>(&Bs[c][tn]);
    acc[0][0] += av.x * bv.x; acc[0][1] += av.x * bv.y; acc[0][2] += av.x * bv.z; acc[0][3] += av.x * bv.w;
    acc[1][0] += av.y * bv.x; acc[1][1] += av.y * bv.y; acc[1][2] += av.y * bv.z; acc[1][3] += av.y * bv.w;
    acc[2][0] += av.z * bv.x; acc[2][1] += av.z * bv.y; acc[2][2] += av.z * bv.z; acc[2][3] += av.z * bv.w;
    acc[3][0] += av.w * bv.x; acc[3][1] += av.w * bv.y; acc[3][2] += av.w * bv.z; acc[3][3] += av.w * bv.w;
  }
  float* dst = (e0 < DM) ? (xc + e0) : (z + (e0 - DM));
#pragma unroll
  for (int i = 0; i < 4; i++) {
    int l = l0 + tm + i;
    float4 v = make_float4(acc[i][0], acc[i][1], acc[i][2], acc[i][3]);
    *reinterpret_cast<float4*>(dst + (size_t)(b * LLEN + l) * DM + tn) = v;
  }
}

// K0: W_comb[160][128]: rows 0..127 = dtw @ xpw[0:4]; rows 128..159 = xpw[4:36]
// Also zeroes the 16-float GN stat buffer (replaces the hipMemsetAsync dispatch).
__global__ __launch_bounds__(256) void k0_wcomb(
    const float* __restrict__ xpw, const float* __restrict__ dtw, float* __restrict__ wc,
    float* __restrict__ stat)
{
  int i = blockIdx.x * 256 + threadIdx.x;
  if (blockIdx.x == 0 && threadIdx.x < BB * NG * 2) stat[threadIdx.x] = 0.f;
  if (i >= 160 * 128) return;
  int e = i >> 7, dd = i & 127;
  float v;
  if (e < 128) {
    v = dtw[e * 4 + 0] * xpw[0 * 128 + dd] + dtw[e * 4 + 1] * xpw[1 * 128 + dd]
      + dtw[e * 4 + 2] * xpw[2 * 128 + dd] + dtw[e * 4 + 3] * xpw[3 * 128 + dd];
  } else {
    v = xpw[(e - 128 + 4) * 128 + dd];
  }
  wc[i] = v;
}

// K2a: u = silu(causal_conv4(xc) + cb). Block = 64 tokens x 128 d; thread = 8 tok x 4 d.
__global__ __launch_bounds__(256) void k2a_conv(
    const float* __restrict__ xc, const float* __restrict__ cw, const float* __restrict__ cb,
    float* __restrict__ u)
{
  const int t = threadIdx.x;
  const int d4 = (t & 31) * 4;
  const int tg = t >> 5;
  const int tok0 = blockIdx.x * 64 + tg * 8;
  const int l0 = tok0 & (LLEN - 1);
  float4 w0 = *reinterpret_cast<const float4*>(cw + (d4 + 0) * 4);
  float4 w1 = *reinterpret_cast<const float4*>(cw + (d4 + 1) * 4);
  float4 w2 = *reinterpret_cast<const float4*>(cw + (d4 + 2) * 4);
  float4 w3 = *reinterpret_cast<const float4*>(cw + (d4 + 3) * 4);
  float4 bias = *reinterpret_cast<const float4*>(cb + d4);
  float4 row[11];
#pragma unroll
  for (int r = 0; r < 11; r++) {
    int l = l0 - 3 + r;
    if (l < 0) row[r] = make_float4(0.f, 0.f, 0.f, 0.f);
    else row[r] = *reinterpret_cast<const float4*>(xc + (size_t)(tok0 - 3 + r) * DM + d4);
  }
#pragma unroll
  for (int j = 0; j < 8; j++) {
    float4 acc;
    acc.x = bias.x + w0.x * row[j].x + w0.y * row[j+1].x + w0.z * row[j+2].x + w0.w * row[j+3].x;
    acc.y = bias.y + w1.x * row[j].y + w1.y * row[j+1].y + w1.z * row[j+2].y + w1.w * row[j+3].y;
    acc.z = bias.z + w2.x * row[j].z + w2.y * row[j+1].z + w2.z * row[j+2].z + w2.w * row[j+3].z;
    acc.w = bias.w + w3.x * row[j].w + w3.y * row[j+1].w + w3.z * row[j+2].w + w3.w * row[j+3].w;
    acc.x = fsilu(acc.x); acc.y = fsilu(acc.y); acc.z = fsilu(acc.z); acc.w = fsilu(acc.w);
    *reinterpret_cast<float4*>(u + (size_t)(tok0 + j) * DM + d4) = acc;
  }
}

// K2b: dbc160 = u @ W_comb^T. M=BL, N=160 (5 tiles of 32), K=128 (2 passes of BK=64).
// 128 threads, micro-tile 4 tok x 4 e; aligned pads (68/36) -> b128 LDS ops;
// staging via 4x4 register transpose (float4 global loads, b128 LDS writes).
__global__ __launch_bounds__(128) void k2b_proj(
    const float* __restrict__ u, const float* __restrict__ wc, const float* __restrict__ dtpb,
    float* __restrict__ dt, float* __restrict__ bm, float* __restrict__ cm)
{
  const int tok0 = blockIdx.x * 64;
  const int e0 = blockIdx.y * 32;
  const int t = threadIdx.x;
  __shared__ float As[64][68];   // [k][tok]
  __shared__ float Bs[64][36];   // [k][e]
  const int tm = (t & 15) * 4;   // token offset
  const int tn = (t >> 4) * 4;   // e offset 0..28
  float acc[4][4] = {};
  for (int kb = 0; kb < 2; kb++) {
    // A staging: 4x4 register transpose. 256 tiles, 2 per thread.
#pragma unroll
    for (int i2 = 0; i2 < 2; i2++) {
      int tile = t + i2 * 128;
      int kt4 = (tile & 15) * 4, tok4 = (tile >> 4) * 4;
      const float* gp = u + (size_t)(tok0 + tok4) * DM + kb * 64 + kt4;
      float4 r0 = *reinterpret_cast<const float4*>(gp + 0 * DM);
      float4 r1 = *reinterpret_cast<const float4*>(gp + 1 * DM);
      float4 r2 = *reinterpret_cast<const float4*>(gp + 2 * DM);
      float4 r3 = *reinterpret_cast<const float4*>(gp + 3 * DM);
      *reinterpret_cast<float4*>(&As[kt4 + 0][tok4]) = make_float4(r0.x, r1.x, r2.x, r3.x);
      *reinterpret_cast<float4*>(&As[kt4 + 1][tok4]) = make_float4(r0.y, r1.y, r2.y, r3.y);
      *reinterpret_cast<float4*>(&As[kt4 + 2][tok4]) = make_float4(r0.z, r1.z, r2.z, r3.z);
      *reinterpret_cast<float4*>(&As[kt4 + 3][tok4]) = make_float4(r0.w, r1.w, r2.w, r3.w);
    }
    // B staging: 4x4 register transpose. 128 tiles, 1 per thread.
    {
      int kt4 = (t & 15) * 4, et4 = (t >> 4) * 4;
      const float* gp = wc + (size_t)(e0 + et4) * DM + kb * 64 + kt4;
      float4 r0 = *reinterpret_cast<const float4*>(gp + 0 * DM);
      float4 r1 = *reinterpret_cast<const float4*>(gp + 1 * DM);
      float4 r2 = *reinterpret_cast<const float4*>(gp + 2 * DM);
      float4 r3 = *reinterpret_cast<const float4*>(gp + 3 * DM);
      *reinterpret_cast<float4*>(&Bs[kt4 + 0][et4]) = make_float4(r0.x, r1.x, r2.x, r3.x);
      *reinterpret_cast<float4*>(&Bs[kt4 + 1][et4]) = make_float4(r0.y, r1.y, r2.y, r3.y);
      *reinterpret_cast<float4*>(&Bs[kt4 + 2][et4]) = make_float4(r0.z, r1.z, r2.z, r3.z);
      *reinterpret_cast<float4*>(&Bs[kt4 + 3][et4]) = make_float4(r0.w, r1.w, r2.w, r3.w);
    }
    __syncthreads();
#pragma unroll 4
    for (int k = 0; k < 64; k++) {
      float4 av = *reinterpret_cast<const float4*>(&As[k][tm]);
      float4 bv = *reinterpret_cast<const float4*>(&Bs[k][tn]);
      acc[0][0] += av.x * bv.x; acc[0][1] += av.x * bv.y; acc[0][2] += av.x * bv.z; acc[0][3] += av.x * bv.w;
      acc[1][0] += av.y * bv.x; acc[1][1] += av.y * bv.y; acc[1][2] += av.y * bv.z; acc[1][3] += av.y * bv.w;
      acc[2][0] += av.z * bv.x; acc[2][1] += av.z * bv.y; acc[2][2] += av.z * bv.z; acc[2][3] += av.z * bv.w;
      acc[3][0] += av.w * bv.x; acc[3][1] += av.w * bv.y; acc[3][2] += av.w * bv.z; acc[3][3] += av.w * bv.w;
    }
    __syncthreads();
  }
  // stage results in LDS (over As memory) for coalesced writeback: Cs[tok][e], stride 33
  float* Cs = &As[0][0];
#pragma unroll
  for (int i = 0; i < 4; i++) {
#pragma unroll
    for (int j = 0; j < 4; j++) Cs[(tm + i) * 33 + tn + j] = acc[i][j];
  }
  __syncthreads();
  if (e0 < DM) {
#pragma unroll
    for (int i = 0; i < 16; i++) {
      int idx = t + i * 128;
      int tok = idx >> 5, e = idx & 31;
      float v = fsoftplus(Cs[tok * 33 + e] + dtpb[e0 + e]);
      dt[(size_t)(tok0 + tok) * DM + e0 + e] = v;
    }
  } else {
#pragma unroll
    for (int i = 0; i < 16; i++) {
      int idx = t + i * 128;
      int tok = idx >> 5, e = idx & 31;
      float v = Cs[tok * 33 + e];
      if (e < 16) bm[(size_t)(tok0 + tok) * 16 + e] = v;
      else        cm[(size_t)(tok0 + tok) * 16 + (e - 16)] = v;
    }
  }
}

// K3: chunk-local scan from h=0. thread = d (16 states in regs); block = (chunk, b)
__global__ __launch_bounds__(128) void k3_scan1(
    const float* __restrict__ dt, const float* __restrict__ u, const float* __restrict__ bm,
    const float* __restrict__ alog, float* __restrict__ hend, float* __restrict__ dts)
{
  const int b = blockIdx.y, ch = blockIdx.x;
  const int d = threadIdx.x;
  __shared__ float sb[TCHK][16];
  const size_t tok0 = (size_t)b * LLEN + (size_t)ch * TCHK;
  reinterpret_cast<float4*>(&sb[0][0])[d] = reinterpret_cast<const float4*>(bm + tok0 * 16)[d];
  float A[16];
  {
    const float4* ap = reinterpret_cast<const float4*>(alog + d * 16);
#pragma unroll
    for (int q = 0; q < 4; q++) {
      float4 v = ap[q];
      A[q * 4 + 0] = -__expf(v.x); A[q * 4 + 1] = -__expf(v.y);
      A[q * 4 + 2] = -__expf(v.z); A[q * 4 + 3] = -__expf(v.w);
    }
  }
  __syncthreads();
  float h[16];
#pragma unroll
  for (int s = 0; s < 16; s++) h[s] = 0.f;
  float dsum = 0.f;
  const float* dtp = dt + tok0 * DM + d;
  const float* up  = u  + tok0 * DM + d;
  for (int i = 0; i < TCHK; i++) {
    float dtv = dtp[(size_t)i * DM];
    float uv  = up[(size_t)i * DM];
    float dtu = dtv * uv;
    dsum += dtv;
    float bv[16];
#pragma unroll
    for (int q = 0; q < 4; q++)
      *reinterpret_cast<float4*>(&bv[q * 4]) = *reinterpret_cast<const float4*>(&sb[i][q * 4]);
#pragma unroll
    for (int s = 0; s < 16; s++) {
      float da = __expf(dtv * A[s]);
      h[s] = da * h[s] + dtu * bv[s];
    }
  }
  float* hp = hend + ((size_t)(b * DM + d) * NCHK + ch) * 16;
#pragma unroll
  for (int q = 0; q < 4; q++)
    reinterpret_cast<float4*>(hp)[q] = make_float4(h[q*4], h[q*4+1], h[q*4+2], h[q*4+3]);
  dts[(size_t)(b * DM + d) * NCHK + ch] = dsum;
}

// K4a: per (bd,g): register-prefetched scan of 16 chunks from h=0.
__global__ __launch_bounds__(256) void k4a_group(
    const float* __restrict__ alog, const float* __restrict__ dts, const float* __restrict__ hend,
    float* __restrict__ hlocal, float* __restrict__ cumdt,
    float* __restrict__ gend, float* __restrict__ gdt)
{
  const int tid = blockIdx.x * 256 + threadIdx.x;  // ((bd*NGRP+g)*16+s)
  const int s = tid & 15;
  const int bdg = tid >> 4;
  const int g = bdg & (NGRP - 1);
  const int bd = bdg >> 5;
  const int d = bd & (DM - 1);
  const float A = -__expf(alog[d * 16 + s]);
  const int ch0 = g * JG;
  const float* hp = hend + ((size_t)bd * NCHK + ch0) * 16 + s;
  const float* dp = dts + (size_t)bd * NCHK + ch0;
  float* hl = hlocal + ((size_t)bd * NCHK + ch0) * 16 + s;
  float hb[JG], db[JG];
#pragma unroll
  for (int j = 0; j < JG; j++) { hb[j] = hp[j * 16]; db[j] = dp[j]; }
  float h = 0.f, cd = 0.f;
#pragma unroll
  for (int j = 0; j < JG; j++) {
    hl[j * 16] = h;
    if (s == 0) cumdt[(size_t)(ch0 + j) * (BB * DM) + bd] = cd;
    h = __expf(A * db[j]) * h + hb[j];
    cd += db[j];
  }
  gend[(size_t)bdg * 16 + s] = h;
  if (s == 0) gdt[bdg] = cd;
}

// K4b: serial combine over 32 group summaries per chain (register-prefetched)
__global__ __launch_bounds__(64) void k4b_combine(
    const float* __restrict__ alog, const float* __restrict__ gdt, const float* __restrict__ gend,
    float* __restrict__ ginit)
{
  const int tid = blockIdx.x * 64 + threadIdx.x;   // bd*16+s
  const int s = tid & 15, bd = tid >> 4, d = bd & (DM - 1);
  const float A = -__expf(alog[d * 16 + s]);
  const float* ge = gend + (size_t)bd * NGRP * 16 + s;
  const float* gd = gdt + (size_t)bd * NGRP;
  float* gi = ginit + (size_t)bd * NGRP * 16 + s;
  float gb[NGRP], db[NGRP];
#pragma unroll
  for (int g = 0; g < NGRP; g++) { gb[g] = ge[g * 16]; db[g] = gd[g]; }
  float h = 0.f;
#pragma unroll
  for (int g = 0; g < NGRP; g++) {
    gi[g * 16] = h;
    h = __expf(A * db[g]) * h + gb[g];
  }
}

// K5: reconstruct h_init = exp(A*cumdt)*ginit + hlocal, then re-scan;
// y = (sum_s h*C + u*D)*silu(z), written in-place over dt
__global__ __launch_bounds__(128) void k5_scan2(
    float* __restrict__ dty, const float* __restrict__ u, const float* __restrict__ bm,
    const float* __restrict__ cm, const float* __restrict__ alog, const float* __restrict__ Dv,
    const float* __restrict__ z, const float* __restrict__ hlocal,
    const float* __restrict__ cumdt, const float* __restrict__ ginit)
{
  const int b = blockIdx.y, ch = blockIdx.x;
  const int d = threadIdx.x;
  __shared__ float sb[TCHK][16], sc[TCHK][16];
  const size_t tok0 = (size_t)b * LLEN + (size_t)ch * TCHK;
  reinterpret_cast<float4*>(&sb[0][0])[d] = reinterpret_cast<const float4*>(bm + tok0 * 16)[d];
  reinterpret_cast<float4*>(&sc[0][0])[d] = reinterpret_cast<const float4*>(cm + tok0 * 16)[d];
  float A[16];
  {
    const float4* ap = reinterpret_cast<const float4*>(alog + d * 16);
#pragma unroll
    for (int q = 0; q < 4; q++) {
      float4 v = ap[q];
      A[q * 4 + 0] = -__expf(v.x); A[q * 4 + 1] = -__expf(v.y);
      A[q * 4 + 2] = -__expf(v.z); A[q * 4 + 3] = -__expf(v.w);
    }
  }
  const float Dd = Dv[d];
  const int bd = b * DM + d;
  const int g = ch / JG;
  const float cd = cumdt[(size_t)ch * (BB * DM) + bd];
  float h[16];
  {
    const float4* hlp = reinterpret_cast<const float4*>(hlocal + ((size_t)bd * NCHK + ch) * 16);
    const float4* gip = reinterpret_cast<const float4*>(ginit + ((size_t)(bd * NGRP + g)) * 16);
#pragma unroll
    for (int q = 0; q < 4; q++) {
      float4 hl = hlp[q];
      float4 gi = gip[q];
      h[q * 4 + 0] = __expf(A[q * 4 + 0] * cd) * gi.x + hl.x;
      h[q * 4 + 1] = __expf(A[q * 4 + 1] * cd) * gi.y + hl.y;
      h[q * 4 + 2] = __expf(A[q * 4 + 2] * cd) * gi.z + hl.z;
      h[q * 4 + 3] = __expf(A[q * 4 + 3] * cd) * gi.w + hl.w;
    }
  }
  __syncthreads();
  float* dtp = dty + tok0 * DM + d;
  const float* up = u + tok0 * DM + d;
  const float* zp = z + tok0 * DM + d;
  for (int i = 0; i < TCHK; i++) {
    float dtv = dtp[(size_t)i * DM];
    float uv  = up[(size_t)i * DM];
    float zv  = zp[(size_t)i * DM];
    float dtu = dtv * uv;
    float bv[16], cv[16];
#pragma unroll
    for (int q = 0; q < 4; q++) {
      *reinterpret_cast<float4*>(&bv[q * 4]) = *reinterpret_cast<const float4*>(&sb[i][q * 4]);
      *reinterpret_cast<float4*>(&cv[q * 4]) = *reinterpret_cast<const float4*>(&sc[i][q * 4]);
    }
    float y = 0.f;
#pragma unroll
    for (int s = 0; s < 16; s++) {
      float da = __expf(dtv * A[s]);
      h[s] = da * h[s] + dtu * bv[s];
      y += h[s] * cv[s];
    }
    y = (y + uv * Dd) * fsilu(zv);
    dtp[(size_t)i * DM] = y;
  }
}

// K6: out = y @ out_proj_w^T + per-(b,group) partial GN stats.
// Aligned pad 68 + 4x4 register-transpose A staging -> b128 LDS ops.
__global__ __launch_bounds__(256) void k6_outproj(
    const float* __restrict__ yv, const float* __restrict__ ow,
    float* __restrict__ ym, float* __restrict__ stat)
{
  const int b = blockIdx.y;
  const int l0 = blockIdx.x * 64;
  const int t = threadIdx.x;
  const int tm = (t & 15) * 4;
  const int tn = (t >> 4) * 4;
  __shared__ float As[64][68];  // [dl][tok]
  __shared__ float Bs[64][68];  // [dl][c]
  float acc[4][4] = {};
  for (int kb = 0; kb < 2; kb++) {
    // A staging: 4x4 register transpose (256 tiles, 1 per thread)
    {
      int dl4 = (t & 15) * 4, tok4 = (t >> 4) * 4;
      const float* gp = yv + (size_t)(b * LLEN + l0 + tok4) * DM + kb * 64 + dl4;
      float4 r0 = *reinterpret_cast<const float4*>(gp + 0 * DM);
      float4 r1 = *reinterpret_cast<const float4*>(gp + 1 * DM);
      float4 r2 = *reinterpret_cast<const float4*>(gp + 2 * DM);
      float4 r3 = *reinterpret_cast<const float4*>(gp + 3 * DM);
      *reinterpret_cast<float4*>(&As[dl4 + 0][tok4]) = make_float4(r0.x, r1.x, r2.x, r3.x);
      *reinterpret_cast<float4*>(&As[dl4 + 1][tok4]) = make_float4(r0.y, r1.y, r2.y, r3.y);
      *reinterpret_cast<float4*>(&As[dl4 + 2][tok4]) = make_float4(r0.z, r1.z, r2.z, r3.z);
      *reinterpret_cast<float4*>(&As[dl4 + 3][tok4]) = make_float4(r0.w, r1.w, r2.w, r3.w);
    }
    // B staging: scalar transpose (one-time)
#pragma unroll
    for (int i = 0; i < 16; i++) {
      int idx = t + i * 256;
      int c = idx >> 6, dl2 = idx & 63;
      Bs[dl2][c] = ow[c * DM + kb * 64 + dl2];
    }
    __syncthreads();
    for (int dl2 = 0; dl2 < 64; dl2++) {
      float4 av = *reinterpret_cast<const float4*>(&As[dl2][tm]);
      float4 bv = *reinterpret_cast<const float4*>(&Bs[dl2][tn]);
      acc[0][0] += av.x * bv.x; acc[0][1] += av.x * bv.y; acc[0][2] += av.x * bv.z; acc[0][3] += av.x * bv.w;
      acc[1][0] += av.y * bv.x; acc[1][1] += av.y * bv.y; acc[1][2] += av.y * bv.z; acc[1][3] += av.y * bv.w;
      acc[2][0] += av.z * bv.x; acc[2][1] += av.z * bv.y; acc[2][2] += av.z * bv.z; acc[2][3] += av.z * bv.w;
      acc[3][0] += av.w * bv.x; acc[3][1] += av.w * bv.y; acc[3][2] += av.w * bv.z; acc[3][3] += av.w * bv.w;
    }
    __syncthreads();
  }
  float lsum = 0.f, lssq = 0.f;
#pragma unroll
  for (int i = 0; i < 4; i++) {
    int l = l0 + tm + i;
    float4 v = make_float4(acc[i][0], acc[i][1], acc[i][2], acc[i][3]);
    *reinterpret_cast<float4*>(ym + (size_t)(b * LLEN + l) * 64 + tn) = v;
    lsum += v.x + v.y + v.z + v.w;
    lssq += v.x * v.x + v.y * v.y + v.z * v.z + v.w * v.w;
  }
  __shared__ float sg[NG * 2];
  if (t < NG * 2) sg[t] = 0.f;
  __syncthreads();
  const int g = tn >> 4;
  atomicAdd(&sg[g * 2 + 0], lsum);
  atomicAdd(&sg[g * 2 + 1], lssq);
  __syncthreads();
  if (t < NG * 2) atomicAdd(&stat[b * NG * 2 + t], sg[t]);
}

// K7: GroupNorm finalize + silu + residual, transpose (b,l,c)->(b,c,l)
__global__ __launch_bounds__(256) void k7_gn(
    const float* __restrict__ ym, const float* __restrict__ stat,
    const float* __restrict__ scale, const float* __restrict__ bias,
    const float* __restrict__ x, float* __restrict__ out)
{
  const int b = blockIdx.y;
  const int p0 = blockIdx.x * 64;
  const int t = threadIdx.x;
  __shared__ float Ts[64][65];
#pragma unroll
  for (int i = 0; i < 16; i++) {
    int idx = t + i * 256;
    int p = idx >> 6, c = idx & 63;
    Ts[c][p] = ym[(size_t)(b * LLEN + p0 + p) * 64 + c];
  }
  __syncthreads();
  const float invN = 1.f / (16.f * 16384.f);
#pragma unroll
  for (int i = 0; i < 16; i++) {
    int idx = t + i * 256;
    int c = idx >> 6, p = idx & 63;
    int g = c >> 4;
    float mu = stat[b * 8 + g * 2] * invN;
    float var = stat[b * 8 + g * 2 + 1] * invN - mu * mu;
    float rs = rsqrtf(var + 1e-5f);
    float v = (Ts[c][p] - mu) * rs * scale[c] + bias[c];
    size_t o = (size_t)(b * CCH + c) * LLEN + p0 + p;
    out[o] = fsilu(v) + x[o];
  }
}

extern "C" void kernel_launch(void* const* d_in, const int* in_sizes, int n_in,
                              void* d_out, int out_size, void* d_ws, size_t ws_size,
                              hipStream_t stream)
{
  const float* x    = (const float*)d_in[0];
  const float* ipw  = (const float*)d_in[1];
  const float* cw   = (const float*)d_in[2];
  const float* cb   = (const float*)d_in[3];
  const float* xpw  = (const float*)d_in[4];
  const float* dtw  = (const float*)d_in[5];
  const float* dtpb = (const float*)d_in[6];
  const float* alog = (const float*)d_in[7];
  const float* Dv   = (const float*)d_in[8];
  const float* ow   = (const float*)d_in[9];
  const float* gns  = (const float*)d_in[10];
  const float* gnb  = (const float*)d_in[11];

  float* ws    = (float*)d_ws;
  float* xc    = ws + OFF_XC;
  float* hend  = ws + OFF_HEND;
  float* hloc  = ws + OFF_HLOC;
  float* z     = ws + OFF_Z;
  float* u     = ws + OFF_U;
  float* dt    = ws + OFF_DT;
  float* bm    = ws + OFF_BM;
  float* cm    = ws + OFF_CM;
  float* dts   = ws + OFF_DTS;
  float* ym    = ws + OFF_YM;
  float* wc    = ws + OFF_WC;
  float* cumdt = ws + OFF_CUMDT;
  float* gend  = ws + OFF_GEND;
  float* gdt   = ws + OFF_GDT;
  float* ginit = ws + OFF_GINIT;
  float* stat  = ws + OFF_STAT;
  float* out   = (float*)d_out;

  k0_wcomb<<<dim3(80), 256, 0, stream>>>(xpw, dtw, wc, stat);
  k1_inproj<<<dim3(LLEN / 64, 4, BB), 256, 0, stream>>>(x, ipw, xc, z);
  k2a_conv<<<dim3(BB * LLEN / 64), 256, 0, stream>>>(xc, cw, cb, u);
  k2b_proj<<<dim3(BB * LLEN / 64, 5), 128, 0, stream>>>(u, wc, dtpb, dt, bm, cm);
  k3_scan1<<<dim3(NCHK, BB), 128, 0, stream>>>(dt, u, bm, alog, hend, dts);
  k4a_group<<<dim3(BB * DM * NGRP * 16 / 256), 256, 0, stream>>>(alog, dts, hend, hloc, cumdt, gend, gdt);
  k4b_combine<<<dim3(BB * DM * 16 / 64), 64, 0, stream>>>(alog, gdt, gend, ginit);
  k5_scan2<<<dim3(NCHK, BB), 128, 0, stream>>>(dt, u, bm, cm, alog, Dv, z, hloc, cumdt, ginit);
  k6_outproj<<<dim3(LLEN / 64, BB), 256, 0, stream>>>(dt, ow, ym, stat);
  k7_gn<<<dim3(LLEN / 64, BB), 256, 0, stream>>>(ym, stat, gns, gnb, x, out);
}

// Round 11
// 133.395 us; speedup vs baseline: 1.3257x; 1.1212x over previous
//
#include <hip/hip_runtime.h>

#define BB 2
#define CCH 64
#define LLEN 16384
#define DM 128
#define NCHK 512
#define TCHK 32
#define NGRP 32
#define JG 16
#define NG 4

// workspace offsets (floats). hend aliases xc (dead after k2); wc aliases ym (dead
// until k5f). k4 scratch moved OUT of ym region (k5f reads them while writing ym).
#define OFF_XC   0ull
#define OFF_HEND 0ull
#define OFF_HLOC 2097152ull
#define OFF_Z    4194304ull
#define OFF_U    8388608ull
#define OFF_DT   12582912ull
#define OFF_BM   16777216ull
#define OFF_CM   17301504ull
#define OFF_DTS  17825792ull
#define OFF_YM   17956864ull
#define OFF_WC   17956864ull
#define OFF_STAT 20054016ull
#define OFF_CUMDT 20971520ull
#define OFF_GEND  21102592ull
#define OFF_GDT   21233664ull
#define OFF_GINIT 21241856ull

__device__ __forceinline__ float fsilu(float v) {
  return v * __builtin_amdgcn_rcpf(1.f + __expf(-v));
}
__device__ __forceinline__ float fsoftplus(float v) {
  return v > 20.f ? v : __logf(1.f + __expf(v));
}

// K1: xz = xr @ in_proj_w^T ; split into xc (e<128) and z (e>=128)
__global__ __launch_bounds__(256) void k1_inproj(
    const float* __restrict__ x, const float* __restrict__ w,
    float* __restrict__ xc, float* __restrict__ z)
{
  const int b = blockIdx.z;
  const int l0 = blockIdx.x * 64;
  const int e0 = blockIdx.y * 64;
  __shared__ float As[64][68];  // [c][tok]
  __shared__ float Bs[64][68];  // [c][e]
  const int t = threadIdx.x;
#pragma unroll
  for (int i = 0; i < 4; i++) {
    int f4 = t + i * 256;
    int c = f4 >> 4, tok4 = (f4 & 15) * 4;
    *reinterpret_cast<float4*>(&As[c][tok4]) =
        *reinterpret_cast<const float4*>(&x[(size_t)(b * CCH + c) * LLEN + l0 + tok4]);
  }
#pragma unroll
  for (int i = 0; i < 16; i++) {
    int idx = t + i * 256;
    int e = idx >> 6, c = idx & 63;
    Bs[c][e] = w[(e0 + e) * CCH + c];
  }
  __syncthreads();
  const int tm = (t & 15) * 4;
  const int tn = (t >> 4) * 4;
  float acc[4][4] = {};
  for (int c = 0; c < 64; c++) {
    float4 av = *reinterpret_cast<const float4*>(&As[c][tm]);
    float4 bv = *reinterpret_cast<const float4*>(&Bs[c][tn]);
    acc[0][0] += av.x * bv.x; acc[0][1] += av.x * bv.y; acc[0][2] += av.x * bv.z; acc[0][3] += av.x * bv.w;
    acc[1][0] += av.y * bv.x; acc[1][1] += av.y * bv.y; acc[1][2] += av.y * bv.z; acc[1][3] += av.y * bv.w;
    acc[2][0] += av.z * bv.x; acc[2][1] += av.z * bv.y; acc[2][2] += av.z * bv.z; acc[2][3] += av.z * bv.w;
    acc[3][0] += av.w * bv.x; acc[3][1] += av.w * bv.y; acc[3][2] += av.w * bv.z; acc[3][3] += av.w * bv.w;
  }
  float* dst = (e0 < DM) ? (xc + e0) : (z + (e0 - DM));
#pragma unroll
  for (int i = 0; i < 4; i++) {
    int l = l0 + tm + i;
    float4 v = make_float4(acc[i][0], acc[i][1], acc[i][2], acc[i][3]);
    *reinterpret_cast<float4*>(dst + (size_t)(b * LLEN + l) * DM + tn) = v;
  }
}

// K0: W_comb[160][128]; also zeroes the GN stat buffer.
__global__ __launch_bounds__(256) void k0_wcomb(
    const float* __restrict__ xpw, const float* __restrict__ dtw, float* __restrict__ wc,
    float* __restrict__ stat)
{
  int i = blockIdx.x * 256 + threadIdx.x;
  if (blockIdx.x == 0 && threadIdx.x < BB * NG * 2) stat[threadIdx.x] = 0.f;
  if (i >= 160 * 128) return;
  int e = i >> 7, dd = i & 127;
  float v;
  if (e < 128) {
    v = dtw[e * 4 + 0] * xpw[0 * 128 + dd] + dtw[e * 4 + 1] * xpw[1 * 128 + dd]
      + dtw[e * 4 + 2] * xpw[2 * 128 + dd] + dtw[e * 4 + 3] * xpw[3 * 128 + dd];
  } else {
    v = xpw[(e - 128 + 4) * 128 + dd];
  }
  wc[i] = v;
}

// K2a: u = silu(causal_conv4(xc) + cb)
__global__ __launch_bounds__(256) void k2a_conv(
    const float* __restrict__ xc, const float* __restrict__ cw, const float* __restrict__ cb,
    float* __restrict__ u)
{
  const int t = threadIdx.x;
  const int d4 = (t & 31) * 4;
  const int tg = t >> 5;
  const int tok0 = blockIdx.x * 64 + tg * 8;
  const int l0 = tok0 & (LLEN - 1);
  float4 w0 = *reinterpret_cast<const float4*>(cw + (d4 + 0) * 4);
  float4 w1 = *reinterpret_cast<const float4*>(cw + (d4 + 1) * 4);
  float4 w2 = *reinterpret_cast<const float4*>(cw + (d4 + 2) * 4);
  float4 w3 = *reinterpret_cast<const float4*>(cw + (d4 + 3) * 4);
  float4 bias = *reinterpret_cast<const float4*>(cb + d4);
  float4 row[11];
#pragma unroll
  for (int r = 0; r < 11; r++) {
    int l = l0 - 3 + r;
    if (l < 0) row[r] = make_float4(0.f, 0.f, 0.f, 0.f);
    else row[r] = *reinterpret_cast<const float4*>(xc + (size_t)(tok0 - 3 + r) * DM + d4);
  }
#pragma unroll
  for (int j = 0; j < 8; j++) {
    float4 acc;
    acc.x = bias.x + w0.x * row[j].x + w0.y * row[j+1].x + w0.z * row[j+2].x + w0.w * row[j+3].x;
    acc.y = bias.y + w1.x * row[j].y + w1.y * row[j+1].y + w1.z * row[j+2].y + w1.w * row[j+3].y;
    acc.z = bias.z + w2.x * row[j].z + w2.y * row[j+1].z + w2.z * row[j+2].z + w2.w * row[j+3].z;
    acc.w = bias.w + w3.x * row[j].w + w3.y * row[j+1].w + w3.z * row[j+2].w + w3.w * row[j+3].w;
    acc.x = fsilu(acc.x); acc.y = fsilu(acc.y); acc.z = fsilu(acc.z); acc.w = fsilu(acc.w);
    *reinterpret_cast<float4*>(u + (size_t)(tok0 + j) * DM + d4) = acc;
  }
}

// K2b: dbc160 = u @ W_comb^T (aligned pads, register-transpose staging)
__global__ __launch_bounds__(128) void k2b_proj(
    const float* __restrict__ u, const float* __restrict__ wc, const float* __restrict__ dtpb,
    float* __restrict__ dt, float* __restrict__ bm, float* __restrict__ cm)
{
  const int tok0 = blockIdx.x * 64;
  const int e0 = blockIdx.y * 32;
  const int t = threadIdx.x;
  __shared__ float As[64][68];
  __shared__ float Bs[64][36];
  const int tm = (t & 15) * 4;
  const int tn = (t >> 4) * 4;
  float acc[4][4] = {};
  for (int kb = 0; kb < 2; kb++) {
#pragma unroll
    for (int i2 = 0; i2 < 2; i2++) {
      int tile = t + i2 * 128;
      int kt4 = (tile & 15) * 4, tok4 = (tile >> 4) * 4;
      const float* gp = u + (size_t)(tok0 + tok4) * DM + kb * 64 + kt4;
      float4 r0 = *reinterpret_cast<const float4*>(gp + 0 * DM);
      float4 r1 = *reinterpret_cast<const float4*>(gp + 1 * DM);
      float4 r2 = *reinterpret_cast<const float4*>(gp + 2 * DM);
      float4 r3 = *reinterpret_cast<const float4*>(gp + 3 * DM);
      *reinterpret_cast<float4*>(&As[kt4 + 0][tok4]) = make_float4(r0.x, r1.x, r2.x, r3.x);
      *reinterpret_cast<float4*>(&As[kt4 + 1][tok4]) = make_float4(r0.y, r1.y, r2.y, r3.y);
      *reinterpret_cast<float4*>(&As[kt4 + 2][tok4]) = make_float4(r0.z, r1.z, r2.z, r3.z);
      *reinterpret_cast<float4*>(&As[kt4 + 3][tok4]) = make_float4(r0.w, r1.w, r2.w, r3.w);
    }
    {
      int kt4 = (t & 15) * 4, et4 = (t >> 4) * 4;
      const float* gp = wc + (size_t)(e0 + et4) * DM + kb * 64 + kt4;
      float4 r0 = *reinterpret_cast<const float4*>(gp + 0 * DM);
      float4 r1 = *reinterpret_cast<const float4*>(gp + 1 * DM);
      float4 r2 = *reinterpret_cast<const float4*>(gp + 2 * DM);
      float4 r3 = *reinterpret_cast<const float4*>(gp + 3 * DM);
      *reinterpret_cast<float4*>(&Bs[kt4 + 0][et4]) = make_float4(r0.x, r1.x, r2.x, r3.x);
      *reinterpret_cast<float4*>(&Bs[kt4 + 1][et4]) = make_float4(r0.y, r1.y, r2.y, r3.y);
      *reinterpret_cast<float4*>(&Bs[kt4 + 2][et4]) = make_float4(r0.z, r1.z, r2.z, r3.z);
      *reinterpret_cast<float4*>(&Bs[kt4 + 3][et4]) = make_float4(r0.w, r1.w, r2.w, r3.w);
    }
    __syncthreads();
#pragma unroll 4
    for (int k = 0; k < 64; k++) {
      float4 av = *reinterpret_cast<const float4*>(&As[k][tm]);
      float4 bv = *reinterpret_cast<const float4*>(&Bs[k][tn]);
      acc[0][0] += av.x * bv.x; acc[0][1] += av.x * bv.y; acc[0][2] += av.x * bv.z; acc[0][3] += av.x * bv.w;
      acc[1][0] += av.y * bv.x; acc[1][1] += av.y * bv.y; acc[1][2] += av.y * bv.z; acc[1][3] += av.y * bv.w;
      acc[2][0] += av.z * bv.x; acc[2][1] += av.z * bv.y; acc[2][2] += av.z * bv.z; acc[2][3] += av.z * bv.w;
      acc[3][0] += av.w * bv.x; acc[3][1] += av.w * bv.y; acc[3][2] += av.w * bv.z; acc[3][3] += av.w * bv.w;
    }
    __syncthreads();
  }
  float* Cs = &As[0][0];
#pragma unroll
  for (int i = 0; i < 4; i++) {
#pragma unroll
    for (int j = 0; j < 4; j++) Cs[(tm + i) * 33 + tn + j] = acc[i][j];
  }
  __syncthreads();
  if (e0 < DM) {
#pragma unroll
    for (int i = 0; i < 16; i++) {
      int idx = t + i * 128;
      int tok = idx >> 5, e = idx & 31;
      float v = fsoftplus(Cs[tok * 33 + e] + dtpb[e0 + e]);
      dt[(size_t)(tok0 + tok) * DM + e0 + e] = v;
    }
  } else {
#pragma unroll
    for (int i = 0; i < 16; i++) {
      int idx = t + i * 128;
      int tok = idx >> 5, e = idx & 31;
      float v = Cs[tok * 33 + e];
      if (e < 16) bm[(size_t)(tok0 + tok) * 16 + e] = v;
      else        cm[(size_t)(tok0 + tok) * 16 + (e - 16)] = v;
    }
  }
}

// K3: chunk-local scan from h=0
__global__ __launch_bounds__(128) void k3_scan1(
    const float* __restrict__ dt, const float* __restrict__ u, const float* __restrict__ bm,
    const float* __restrict__ alog, float* __restrict__ hend, float* __restrict__ dts)
{
  const int b = blockIdx.y, ch = blockIdx.x;
  const int d = threadIdx.x;
  __shared__ float sb[TCHK][16];
  const size_t tok0 = (size_t)b * LLEN + (size_t)ch * TCHK;
  reinterpret_cast<float4*>(&sb[0][0])[d] = reinterpret_cast<const float4*>(bm + tok0 * 16)[d];
  float A[16];
  {
    const float4* ap = reinterpret_cast<const float4*>(alog + d * 16);
#pragma unroll
    for (int q = 0; q < 4; q++) {
      float4 v = ap[q];
      A[q * 4 + 0] = -__expf(v.x); A[q * 4 + 1] = -__expf(v.y);
      A[q * 4 + 2] = -__expf(v.z); A[q * 4 + 3] = -__expf(v.w);
    }
  }
  __syncthreads();
  float h[16];
#pragma unroll
  for (int s = 0; s < 16; s++) h[s] = 0.f;
  float dsum = 0.f;
  const float* dtp = dt + tok0 * DM + d;
  const float* up  = u  + tok0 * DM + d;
  for (int i = 0; i < TCHK; i++) {
    float dtv = dtp[(size_t)i * DM];
    float uv  = up[(size_t)i * DM];
    float dtu = dtv * uv;
    dsum += dtv;
    float bv[16];
#pragma unroll
    for (int q = 0; q < 4; q++)
      *reinterpret_cast<float4*>(&bv[q * 4]) = *reinterpret_cast<const float4*>(&sb[i][q * 4]);
#pragma unroll
    for (int s = 0; s < 16; s++) {
      float da = __expf(dtv * A[s]);
      h[s] = da * h[s] + dtu * bv[s];
    }
  }
  float* hp = hend + ((size_t)(b * DM + d) * NCHK + ch) * 16;
#pragma unroll
  for (int q = 0; q < 4; q++)
    reinterpret_cast<float4*>(hp)[q] = make_float4(h[q*4], h[q*4+1], h[q*4+2], h[q*4+3]);
  dts[(size_t)(b * DM + d) * NCHK + ch] = dsum;
}

// K4a: per (bd,g): register-prefetched scan of 16 chunks from h=0
__global__ __launch_bounds__(256) void k4a_group(
    const float* __restrict__ alog, const float* __restrict__ dts, const float* __restrict__ hend,
    float* __restrict__ hlocal, float* __restrict__ cumdt,
    float* __restrict__ gend, float* __restrict__ gdt)
{
  const int tid = blockIdx.x * 256 + threadIdx.x;
  const int s = tid & 15;
  const int bdg = tid >> 4;
  const int g = bdg & (NGRP - 1);
  const int bd = bdg >> 5;
  const int d = bd & (DM - 1);
  const float A = -__expf(alog[d * 16 + s]);
  const int ch0 = g * JG;
  const float* hp = hend + ((size_t)bd * NCHK + ch0) * 16 + s;
  const float* dp = dts + (size_t)bd * NCHK + ch0;
  float* hl = hlocal + ((size_t)bd * NCHK + ch0) * 16 + s;
  float hb[JG], db[JG];
#pragma unroll
  for (int j = 0; j < JG; j++) { hb[j] = hp[j * 16]; db[j] = dp[j]; }
  float h = 0.f, cd = 0.f;
#pragma unroll
  for (int j = 0; j < JG; j++) {
    hl[j * 16] = h;
    if (s == 0) cumdt[(size_t)(ch0 + j) * (BB * DM) + bd] = cd;
    h = __expf(A * db[j]) * h + hb[j];
    cd += db[j];
  }
  gend[(size_t)bdg * 16 + s] = h;
  if (s == 0) gdt[bdg] = cd;
}

// K4b: serial combine over 32 group summaries per chain
__global__ __launch_bounds__(64) void k4b_combine(
    const float* __restrict__ alog, const float* __restrict__ gdt, const float* __restrict__ gend,
    float* __restrict__ ginit)
{
  const int tid = blockIdx.x * 64 + threadIdx.x;
  const int s = tid & 15, bd = tid >> 4, d = bd & (DM - 1);
  const float A = -__expf(alog[d * 16 + s]);
  const float* ge = gend + (size_t)bd * NGRP * 16 + s;
  const float* gd = gdt + (size_t)bd * NGRP;
  float* gi = ginit + (size_t)bd * NGRP * 16 + s;
  float gb[NGRP], db[NGRP];
#pragma unroll
  for (int g = 0; g < NGRP; g++) { gb[g] = ge[g * 16]; db[g] = gd[g]; }
  float h = 0.f;
#pragma unroll
  for (int g = 0; g < NGRP; g++) {
    gi[g * 16] = h;
    h = __expf(A * db[g]) * h + gb[g];
  }
}

// K5f: fused re-scan + gating + out_proj GEMM + GN partial stats.
// Block = 256 threads = 2 chunks (64 tokens); thread (ch2 = t>>7, d = t&127).
// Scan writes y^T into Ys[128][72]; then 64tok x 64c GEMM from Ys / ow^T.
__global__ __launch_bounds__(256) void k5f_scan_out(
    const float* __restrict__ dt, const float* __restrict__ u, const float* __restrict__ bm,
    const float* __restrict__ cm, const float* __restrict__ alog, const float* __restrict__ Dv,
    const float* __restrict__ z, const float* __restrict__ hlocal,
    const float* __restrict__ cumdt, const float* __restrict__ ginit,
    const float* __restrict__ ow, float* __restrict__ ym, float* __restrict__ stat)
{
  const int b = blockIdx.y, bx = blockIdx.x;
  const int t = threadIdx.x;
  const int ch2 = t >> 7;
  const int d = t & 127;
  const int ch = bx * 2 + ch2;
  __shared__ float sb[2][TCHK][16];
  __shared__ float sc[2][TCHK][16];
  __shared__ float Ys[DM][72];   // y^T [d][tok], row 16B-aligned
  __shared__ float Bs[DM][68];   // ow^T [d][c]
  const size_t tokb = (size_t)b * LLEN + (size_t)bx * 64;
  const size_t tok0 = tokb + (size_t)ch2 * TCHK;
  // stage bm/cm for both chunks (1 float4/thread)
  reinterpret_cast<float4*>(&sb[0][0][0])[t] = reinterpret_cast<const float4*>(bm + tokb * 16)[t];
  reinterpret_cast<float4*>(&sc[0][0][0])[t] = reinterpret_cast<const float4*>(cm + tokb * 16)[t];
  // stage ow^T via 4x4 register transpose: 32x16=512 tiles, 2/thread
#pragma unroll
  for (int i2 = 0; i2 < 2; i2++) {
    int tile = t + i2 * 256;
    int c4 = (tile & 15) * 4;
    int dl4 = (tile >> 4) * 4;
    const float* gp = ow + (size_t)c4 * DM + dl4;
    float4 r0 = *reinterpret_cast<const float4*>(gp + 0 * DM);
    float4 r1 = *reinterpret_cast<const float4*>(gp + 1 * DM);
    float4 r2 = *reinterpret_cast<const float4*>(gp + 2 * DM);
    float4 r3 = *reinterpret_cast<const float4*>(gp + 3 * DM);
    *reinterpret_cast<float4*>(&Bs[dl4 + 0][c4]) = make_float4(r0.x, r1.x, r2.x, r3.x);
    *reinterpret_cast<float4*>(&Bs[dl4 + 1][c4]) = make_float4(r0.y, r1.y, r2.y, r3.y);
    *reinterpret_cast<float4*>(&Bs[dl4 + 2][c4]) = make_float4(r0.z, r1.z, r2.z, r3.z);
    *reinterpret_cast<float4*>(&Bs[dl4 + 3][c4]) = make_float4(r0.w, r1.w, r2.w, r3.w);
  }
  float A[16];
  {
    const float4* ap = reinterpret_cast<const float4*>(alog + d * 16);
#pragma unroll
    for (int q = 0; q < 4; q++) {
      float4 v = ap[q];
      A[q * 4 + 0] = -__expf(v.x); A[q * 4 + 1] = -__expf(v.y);
      A[q * 4 + 2] = -__expf(v.z); A[q * 4 + 3] = -__expf(v.w);
    }
  }
  const float Dd = Dv[d];
  const int bd = b * DM + d;
  const int g = ch / JG;
  const float cd = cumdt[(size_t)ch * (BB * DM) + bd];
  float h[16];
  {
    const float4* hlp = reinterpret_cast<const float4*>(hlocal + ((size_t)bd * NCHK + ch) * 16);
    const float4* gip = reinterpret_cast<const float4*>(ginit + ((size_t)(bd * NGRP + g)) * 16);
#pragma unroll
    for (int q = 0; q < 4; q++) {
      float4 hl = hlp[q];
      float4 gi = gip[q];
      h[q * 4 + 0] = __expf(A[q * 4 + 0] * cd) * gi.x + hl.x;
      h[q * 4 + 1] = __expf(A[q * 4 + 1] * cd) * gi.y + hl.y;
      h[q * 4 + 2] = __expf(A[q * 4 + 2] * cd) * gi.z + hl.z;
      h[q * 4 + 3] = __expf(A[q * 4 + 3] * cd) * gi.w + hl.w;
    }
  }
  __syncthreads();
  const float* dtp = dt + tok0 * DM + d;
  const float* up = u + tok0 * DM + d;
  const float* zp = z + tok0 * DM + d;
  for (int i = 0; i < TCHK; i++) {
    float dtv = dtp[(size_t)i * DM];
    float uv  = up[(size_t)i * DM];
    float zv  = zp[(size_t)i * DM];
    float dtu = dtv * uv;
    float bv[16], cv[16];
#pragma unroll
    for (int q = 0; q < 4; q++) {
      *reinterpret_cast<float4*>(&bv[q * 4]) = *reinterpret_cast<const float4*>(&sb[ch2][i][q * 4]);
      *reinterpret_cast<float4*>(&cv[q * 4]) = *reinterpret_cast<const float4*>(&sc[ch2][i][q * 4]);
    }
    float y = 0.f;
#pragma unroll
    for (int s = 0; s < 16; s++) {
      float da = __expf(dtv * A[s]);
      h[s] = da * h[s] + dtu * bv[s];
      y += h[s] * cv[s];
    }
    Ys[d][ch2 * TCHK + i] = (y + uv * Dd) * fsilu(zv);
  }
  __syncthreads();
  // out-proj GEMM: 64 tok x 64 c, K = 128
  const int tm = (t & 15) * 4;
  const int tn = (t >> 4) * 4;
  float acc[4][4] = {};
  for (int k = 0; k < DM; k++) {
    float4 av = *reinterpret_cast<const float4*>(&Ys[k][tm]);
    float4 bv = *reinterpret_cast<const float4*>(&Bs[k][tn]);
    acc[0][0] += av.x * bv.x; acc[0][1] += av.x * bv.y; acc[0][2] += av.x * bv.z; acc[0][3] += av.x * bv.w;
    acc[1][0] += av.y * bv.x; acc[1][1] += av.y * bv.y; acc[1][2] += av.y * bv.z; acc[1][3] += av.y * bv.w;
    acc[2][0] += av.z * bv.x; acc[2][1] += av.z * bv.y; acc[2][2] += av.z * bv.z; acc[2][3] += av.z * bv.w;
    acc[3][0] += av.w * bv.x; acc[3][1] += av.w * bv.y; acc[3][2] += av.w * bv.z; acc[3][3] += av.w * bv.w;
  }
  float lsum = 0.f, lssq = 0.f;
#pragma unroll
  for (int i = 0; i < 4; i++) {
    float4 v = make_float4(acc[i][0], acc[i][1], acc[i][2], acc[i][3]);
    *reinterpret_cast<float4*>(ym + (tokb + tm + i) * 64 + tn) = v;
    lsum += v.x + v.y + v.z + v.w;
    lssq += v.x * v.x + v.y * v.y + v.z * v.z + v.w * v.w;
  }
  __shared__ float sg[NG * 2];
  if (t < NG * 2) sg[t] = 0.f;
  __syncthreads();
  const int gg = tn >> 4;
  atomicAdd(&sg[gg * 2 + 0], lsum);
  atomicAdd(&sg[gg * 2 + 1], lssq);
  __syncthreads();
  if (t < NG * 2) atomicAdd(&stat[b * NG * 2 + t], sg[t]);
}

// K7: GroupNorm finalize + silu + residual, transpose (b,l,c)->(b,c,l)
__global__ __launch_bounds__(256) void k7_gn(
    const float* __restrict__ ym, const float* __restrict__ stat,
    const float* __restrict__ scale, const float* __restrict__ bias,
    const float* __restrict__ x, float* __restrict__ out)
{
  const int b = blockIdx.y;
  const int p0 = blockIdx.x * 64;
  const int t = threadIdx.x;
  __shared__ float Ts[64][65];
#pragma unroll
  for (int i = 0; i < 16; i++) {
    int idx = t + i * 256;
    int p = idx >> 6, c = idx & 63;
    Ts[c][p] = ym[(size_t)(b * LLEN + p0 + p) * 64 + c];
  }
  __syncthreads();
  const float invN = 1.f / (16.f * 16384.f);
#pragma unroll
  for (int i = 0; i < 16; i++) {
    int idx = t + i * 256;
    int c = idx >> 6, p = idx & 63;
    int g = c >> 4;
    float mu = stat[b * 8 + g * 2] * invN;
    float var = stat[b * 8 + g * 2 + 1] * invN - mu * mu;
    float rs = rsqrtf(var + 1e-5f);
    float v = (Ts[c][p] - mu) * rs * scale[c] + bias[c];
    size_t o = (size_t)(b * CCH + c) * LLEN + p0 + p;
    out[o] = fsilu(v) + x[o];
  }
}

extern "C" void kernel_launch(void* const* d_in, const int* in_sizes, int n_in,
                              void* d_out, int out_size, void* d_ws, size_t ws_size,
                              hipStream_t stream)
{
  const float* x    = (const float*)d_in[0];
  const float* ipw  = (const float*)d_in[1];
  const float* cw   = (const float*)d_in[2];
  const float* cb   = (const float*)d_in[3];
  const float* xpw  = (const float*)d_in[4];
  const float* dtw  = (const float*)d_in[5];
  const float* dtpb = (const float*)d_in[6];
  const float* alog = (const float*)d_in[7];
  const float* Dv   = (const float*)d_in[8];
  const float* ow   = (const float*)d_in[9];
  const float* gns  = (const float*)d_in[10];
  const float* gnb  = (const float*)d_in[11];

  float* ws    = (float*)d_ws;
  float* xc    = ws + OFF_XC;
  float* hend  = ws + OFF_HEND;
  float* hloc  = ws + OFF_HLOC;
  float* z     = ws + OFF_Z;
  float* u     = ws + OFF_U;
  float* dt    = ws + OFF_DT;
  float* bm    = ws + OFF_BM;
  float* cm    = ws + OFF_CM;
  float* dts   = ws + OFF_DTS;
  float* ym    = ws + OFF_YM;
  float* wc    = ws + OFF_WC;
  float* cumdt = ws + OFF_CUMDT;
  float* gend  = ws + OFF_GEND;
  float* gdt   = ws + OFF_GDT;
  float* ginit = ws + OFF_GINIT;
  float* stat  = ws + OFF_STAT;
  float* out   = (float*)d_out;

  k0_wcomb<<<dim3(80), 256, 0, stream>>>(xpw, dtw, wc, stat);
  k1_inproj<<<dim3(LLEN / 64, 4, BB), 256, 0, stream>>>(x, ipw, xc, z);
  k2a_conv<<<dim3(BB * LLEN / 64), 256, 0, stream>>>(xc, cw, cb, u);
  k2b_proj<<<dim3(BB * LLEN / 64, 5), 128, 0, stream>>>(u, wc, dtpb, dt, bm, cm);
  k3_scan1<<<dim3(NCHK, BB), 128, 0, stream>>>(dt, u, bm, alog, hend, dts);
  k4a_group<<<dim3(BB * DM * NGRP * 16 / 256), 256, 0, stream>>>(alog, dts, hend, hloc, cumdt, gend, gdt);
  k4b_combine<<<dim3(BB * DM * 16 / 64), 64, 0, stream>>>(alog, gdt, gend, ginit);
  k5f_scan_out<<<dim3(NCHK / 2, BB), 256, 0, stream>>>(dt, u, bm, cm, alog, Dv, z, hloc, cumdt, ginit, ow, ym, stat);
  k7_gn<<<dim3(LLEN / 64, BB), 256, 0, stream>>>(ym, stat, gns, gnb, x, out);
}